// Round 3
// baseline (2706.825 us; speedup 1.0000x reference)
//
#include <hip/hip_runtime.h>
#include <hip/hip_bf16.h>
#include <math.h>

#define B_  2
#define T_  4096
#define D_  1024
#define HD_ 128
#define HQ_ 8
#define W_  1024
#define HH_ 1536
#define HG_ 2048
#define KC_ 4

typedef float  f32x4  __attribute__((ext_vector_type(4)));
typedef float  f32x2  __attribute__((ext_vector_type(2)));
typedef __bf16 bf16x8 __attribute__((ext_vector_type(8)));
typedef unsigned short u16x4 __attribute__((ext_vector_type(4)));

__device__ __forceinline__ unsigned short f2bf(float f) {
    unsigned int u = __builtin_bit_cast(unsigned int, f);
    u += 0x7fffu + ((u >> 16) & 1u);           // round-to-nearest-even
    return (unsigned short)(u >> 16);
}
__device__ __forceinline__ float gelu_exact(float x) {
    return 0.5f * x * (1.0f + erff(x * 0.70710678118654752f));
}
__device__ __forceinline__ float sigmoidf_(float x) {
    return 1.0f / (1.0f + expf(-x));
}

// ---------------------------------------------------------------------------
// GEMM: out[M][N] = X[M][K] @ W[N][K]^T with fused epilogues.
// EPI: 0 none | 1 +bias | 2 +res | 3 glu: out=gelu(gatebuf)*acc (gatebuf==out)
//      4 gatex: ig=acc+bias; fg=gatebuf; alpha=exp(-8*softplus(fb)*sig(fg));
//               alphaout=alpha (==gatebuf); out=sqrt(1-a^2+1e-6)*sig(ig)*xc
// bf16 MFMA 16x16x32, 128x128 tile, BK=32, 4 waves (2x2), 64x64 per wave.
// ---------------------------------------------------------------------------
#define LPAD 40
template<int EPI>
__global__ __launch_bounds__(256)
void gemm_kernel(const float* __restrict__ X, const float* __restrict__ Wt,
                 const float* __restrict__ bias, const float* res,
                 const float* gatebuf, const float* __restrict__ xc,
                 const float* __restrict__ fb, float* alphaout,
                 float* out, int M, int N, int K)
{
    __shared__ unsigned short lA[128 * LPAD];
    __shared__ unsigned short lB[128 * LPAD];

    const int n0 = blockIdx.x * 128;
    const int m0 = blockIdx.y * 128;
    const int tid = threadIdx.x;
    const int w = tid >> 6, l = tid & 63;
    const int wr = w >> 1, wc = w & 1;
    const int lr = l & 15, lg = l >> 4;

    f32x4 acc[4][4];
#pragma unroll
    for (int i = 0; i < 4; i++)
#pragma unroll
        for (int j = 0; j < 4; j++) acc[i][j] = {0.f, 0.f, 0.f, 0.f};

    const int trow = tid >> 3;            // 0..31
    const int tcol = (tid & 7) * 4;       // 0,4,..28
    const float* Xp = X + (long)(m0 + trow) * K + tcol;
    const float* Wp = Wt + (long)(n0 + trow) * K + tcol;
    unsigned short* law = &lA[trow * LPAD + tcol];
    unsigned short* lbw = &lB[trow * LPAD + tcol];

    for (int kk = 0; kk < K; kk += 32) {
        __syncthreads();
#pragma unroll
        for (int r = 0; r < 4; r++) {
            f32x4 a = *(const f32x4*)(Xp + (long)(r * 32) * K + kk);
            f32x4 b = *(const f32x4*)(Wp + (long)(r * 32) * K + kk);
            u16x4 av, bv;
            av.x = f2bf(a.x); av.y = f2bf(a.y); av.z = f2bf(a.z); av.w = f2bf(a.w);
            bv.x = f2bf(b.x); bv.y = f2bf(b.y); bv.z = f2bf(b.z); bv.w = f2bf(b.w);
            *(u16x4*)(law + r * 32 * LPAD) = av;
            *(u16x4*)(lbw + r * 32 * LPAD) = bv;
        }
        __syncthreads();

        bf16x8 afr[4], bfr[4];
#pragma unroll
        for (int m = 0; m < 4; m++)
            afr[m] = *(const bf16x8*)&lA[(wr * 64 + m * 16 + lr) * LPAD + lg * 8];
#pragma unroll
        for (int n = 0; n < 4; n++)
            bfr[n] = *(const bf16x8*)&lB[(wc * 64 + n * 16 + lr) * LPAD + lg * 8];
#pragma unroll
        for (int m = 0; m < 4; m++)
#pragma unroll
            for (int n = 0; n < 4; n++)
                acc[m][n] = __builtin_amdgcn_mfma_f32_16x16x32_bf16(afr[m], bfr[n], acc[m][n], 0, 0, 0);
    }

#pragma unroll
    for (int m = 0; m < 4; m++)
#pragma unroll
        for (int n = 0; n < 4; n++) {
            const int col = n0 + wc * 64 + n * 16 + lr;
            float bv = (EPI == 1 || EPI == 4) ? bias[col] : 0.f;
            float spv = 0.f;
            if (EPI == 4) {
                float f = fb[col];
                spv = (f > 20.f) ? f : log1pf(expf(f));
            }
#pragma unroll
            for (int r = 0; r < 4; r++) {
                const int row = m0 + wr * 64 + m * 16 + lg * 4 + r;
                const long idx = (long)row * N + col;
                float v = acc[m][n][r] + bv;
                if (EPI == 2) v += res[idx];
                if (EPI == 3) v = gelu_exact(gatebuf[idx]) * v;
                if (EPI == 4) {
                    float fg = gatebuf[idx];
                    float a = expf(-8.0f * spv * sigmoidf_(fg));
                    alphaout[idx] = a;
                    v = sqrtf(1.f - a * a + 1e-6f) * sigmoidf_(v) * xc[idx];
                }
                out[idx] = v;
            }
        }
}

// ---------------------------------------------------------------------------
// RMSNorm: out = g * sqrt(D) * x * rsqrt(sum(x^2)), one block per row
// ---------------------------------------------------------------------------
__global__ __launch_bounds__(256)
void rmsnorm_kernel(const float* __restrict__ x, const float* __restrict__ g,
                    float* __restrict__ out)
{
    const long row = blockIdx.x;
    const int tid = threadIdx.x;
    const float* xp = x + row * D_;
    f32x4 v = *(const f32x4*)(xp + tid * 4);
    float ss = v.x * v.x + v.y * v.y + v.z * v.z + v.w * v.w;
#pragma unroll
    for (int o = 1; o < 64; o <<= 1) ss += __shfl_xor(ss, o);
    __shared__ float ps[4];
    if ((tid & 63) == 0) ps[tid >> 6] = ss;
    __syncthreads();
    float tot = ps[0] + ps[1] + ps[2] + ps[3];
    float inv = rsqrtf(tot) * 32.0f;     // sqrt(1024)=32
    f32x4 gv = *(const f32x4*)(g + tid * 4);
    f32x4 o4;
    o4.x = gv.x * v.x * inv; o4.y = gv.y * v.y * inv;
    o4.z = gv.z * v.z * inv; o4.w = gv.w * v.w * inv;
    *(f32x4*)(out + row * D_ + tid * 4) = o4;
}

// ---------------------------------------------------------------------------
// RoPE (in-place on q and the k half of kv)
// q: [B,T,HQ,128], kv: [B,T,2,128]
// ---------------------------------------------------------------------------
__global__ void rope_kernel(float* __restrict__ q, float* __restrict__ kv)
{
    const long NQ = (long)B_ * T_ * HQ_ * 64;
    const long NK = (long)B_ * T_ * 64;
    long idx = (long)blockIdx.x * blockDim.x + threadIdx.x;
    if (idx >= NQ + NK) return;
    int i; long t; float* ptr;
    if (idx < NQ) {
        i = idx & 63;
        long bth = idx >> 6;            // (b*T+t)*HQ + h
        t = (bth / HQ_) % T_;
        ptr = q + bth * HD_ + 2 * i;
    } else {
        long k = idx - NQ;
        i = k & 63;
        long bt = k >> 6;               // b*T + t
        t = bt % T_;
        ptr = kv + bt * (2 * HD_) + 2 * i;
    }
    float freq = exp2f(-(float)i * 0.20762050593046014f);  // log2(1e4)/64
    float ang = (float)t * freq;
    float sn, cs;
    sincosf(ang, &sn, &cs);
    f32x2 xv = *(f32x2*)ptr;
    f32x2 yv;
    yv.x = xv.x * cs - xv.y * sn;
    yv.y = xv.x * sn + xv.y * cs;
    *(f32x2*)ptr = yv;
}

// ---------------------------------------------------------------------------
// Sliding-window attention (f32, online softmax)
// block = (64 queries, head, b); 4 threads per query (32 dims each)
// ---------------------------------------------------------------------------
__global__ __launch_bounds__(256)
void attn_kernel(const float* __restrict__ q, const float* __restrict__ kv,
                 float* __restrict__ o)
{
    const int qt = blockIdx.x, h = blockIdx.y, b = blockIdx.z;
    const int q0 = qt * 64;
    const int tid = threadIdx.x;
    const int g = tid >> 2, c = tid & 3;
    const int qpos = q0 + g;

    __shared__ float Kt[64][128];
    __shared__ float Vt[64][128];

    f32x4 qv[8], ov[8];
    const float* qp = q + (((long)b * T_ + qpos) * HQ_ + h) * HD_ + c * 32;
#pragma unroll
    for (int j = 0; j < 8; j++) { qv[j] = *(const f32x4*)(qp + 4 * j); ov[j] = {0.f, 0.f, 0.f, 0.f}; }

    float mrun = -1e30f, srun = 0.f;
    const float scale = 0.0883883476483184f;   // 128^-0.5
    int k_lo = q0 - W_; if (k_lo < 0) k_lo = 0;

    for (int kt0 = k_lo; kt0 <= q0; kt0 += 64) {
        __syncthreads();
#pragma unroll
        for (int r = 0; r < 8; r++) {
            int f4 = tid + r * 256;
            int krow = f4 >> 5, d4 = (f4 & 31) * 4;
            const float* kp = kv + (((long)b * T_ + kt0 + krow) * 2) * HD_ + d4;
            *(f32x4*)&Kt[krow][d4] = *(const f32x4*)kp;
            *(f32x4*)&Vt[krow][d4] = *(const f32x4*)(kp + HD_);
        }
        __syncthreads();

        for (int kk = 0; kk < 64; kk++) {
            int kpos = kt0 + kk;
            float d = 0.f;
#pragma unroll
            for (int j = 0; j < 8; j++) {
                f32x4 kvv = *(const f32x4*)&Kt[kk][c * 32 + 4 * j];
                d += qv[j].x * kvv.x + qv[j].y * kvv.y + qv[j].z * kvv.z + qv[j].w * kvv.w;
            }
            d += __shfl_xor(d, 1);
            d += __shfl_xor(d, 2);
            float s = d * scale;
            bool valid = (kpos <= qpos) && (kpos >= qpos - W_);
            if (valid) {
                if (s > mrun) {
                    float f = __expf(mrun - s);
                    mrun = s;
                    srun *= f;
#pragma unroll
                    for (int j = 0; j < 8; j++) ov[j] *= f;
                }
                float p = __expf(s - mrun);
                srun += p;
#pragma unroll
                for (int j = 0; j < 8; j++) {
                    f32x4 vv = *(const f32x4*)&Vt[kk][c * 32 + 4 * j];
                    ov[j] += p * vv;
                }
            }
        }
    }
    float inv = 1.f / srun;
    float* op = o + ((long)b * T_ + qpos) * (HQ_ * HD_) + h * HD_ + c * 32;
#pragma unroll
    for (int j = 0; j < 8; j++) *(f32x4*)(op + 4 * j) = ov[j] * inv;
}

// ---------------------------------------------------------------------------
// GLU: out[r][c] = gelu(gate[r][c]) * h[r][c]
// ---------------------------------------------------------------------------
__global__ void glu_kernel(const float* __restrict__ gate, const float* h,
                           float* out, int gs, int hs, int os,
                           int cols4, long nrows)
{
    long idx = (long)blockIdx.x * blockDim.x + threadIdx.x;
    long total = nrows * cols4;
    if (idx >= total) return;
    long r = idx / cols4;
    int c = (int)(idx % cols4) * 4;
    f32x4 gv = *(const f32x4*)(gate + r * gs + c);
    f32x4 hv = *(const f32x4*)(h + r * hs + c);
    f32x4 o4;
    o4.x = gelu_exact(gv.x) * hv.x;
    o4.y = gelu_exact(gv.y) * hv.y;
    o4.z = gelu_exact(gv.z) * hv.z;
    o4.w = gelu_exact(gv.w) * hv.w;
    *(f32x4*)(out + r * os + c) = o4;
}

// ---------------------------------------------------------------------------
// Depthwise causal conv K=4 over u [8192,1536] (stride HH_)
// ---------------------------------------------------------------------------
__global__ void conv_kernel(const float* __restrict__ u, const float* __restrict__ w,
                            const float* __restrict__ bias, float* __restrict__ xc)
{
    long idx = (long)blockIdx.x * blockDim.x + threadIdx.x;
    if (idx >= (long)B_ * T_ * HH_) return;
    int ch = (int)(idx % HH_);
    long row = idx / HH_;                 // b*T + t
    int t = (int)(row % T_);
    float acc = bias[ch];
#pragma unroll
    for (int k = 0; k < KC_; k++) {
        int ts = t - 3 + k;
        if (ts >= 0) acc += u[(row - t + ts) * HH_ + ch] * w[ch * KC_ + k];
    }
    xc[row * HH_ + ch] = acc;
}

// ---------------------------------------------------------------------------
// Chunked scan: h_t = a_t h_{t-1} + x_t, per (b,ch). CS=64, NC=64.
// alpha/xin are [8192,1536] row-major (stride HH_).
// ---------------------------------------------------------------------------
#define CS_ 64
#define NC_ (T_ / CS_)
__global__ void scan1_kernel(const float* __restrict__ alpha, const float* __restrict__ xin,
                             float* __restrict__ P, float* __restrict__ L)
{
    long idx = (long)blockIdx.x * blockDim.x + threadIdx.x;
    if (idx >= (long)B_ * NC_ * HH_) return;
    int ch = (int)(idx % HH_);
    int chunk = (int)((idx / HH_) % NC_);
    int b = (int)(idx / ((long)HH_ * NC_));
    long base = ((long)b * T_ + chunk * CS_) * HH_ + ch;
    float p = 1.f, l = 0.f;
    for (int i = 0; i < CS_; i++) {
        float a = alpha[base + (long)i * HH_];
        float x = xin[base + (long)i * HH_];
        l = a * l + x;
        p *= a;
    }
    P[idx] = p; L[idx] = l;
}
__global__ void scan2_kernel(const float* __restrict__ P, const float* __restrict__ L,
                             float* __restrict__ I)
{
    long idx = (long)blockIdx.x * blockDim.x + threadIdx.x;
    if (idx >= (long)B_ * HH_) return;
    int ch = (int)(idx % HH_);
    int b = (int)(idx / HH_);
    float init = 0.f;
    for (int c = 0; c < NC_; c++) {
        long o = ((long)b * NC_ + c) * HH_ + ch;
        I[o] = init;
        init = P[o] * init + L[o];
    }
}
__global__ void scan3_kernel(const float* __restrict__ alpha, const float* __restrict__ I,
                             float* __restrict__ xin /* becomes h */)
{
    long idx = (long)blockIdx.x * blockDim.x + threadIdx.x;
    if (idx >= (long)B_ * NC_ * HH_) return;
    int ch = (int)(idx % HH_);
    int chunk = (int)((idx / HH_) % NC_);
    int b = (int)(idx / ((long)HH_ * NC_));
    long base = ((long)b * T_ + chunk * CS_) * HH_ + ch;
    float hcur = I[idx];
    for (int i = 0; i < CS_; i++) {
        long o = base + (long)i * HH_;
        hcur = alpha[o] * hcur + xin[o];
        xin[o] = hcur;
    }
}

// ---------------------------------------------------------------------------
// launch — workspace layout (floats):
//   R1 [0 .. 25,165,824)      : Q|KV|AT / mlp GATE / hawk GATE|U->ALPHA
//   R2 [25,165,824 .. 50,331,648) : XN / hawk XC|XIN
//   R4 [50,331,648 .. 50,921,472) : scan P,L,I
// total 203,685,888 bytes
// ---------------------------------------------------------------------------
static inline long cdivl(long a, long b) { return (a + b - 1) / b; }

extern "C" void kernel_launch(void* const* d_in, const int* in_sizes, int n_in,
                              void* d_out, int out_size, void* d_ws, size_t ws_size,
                              hipStream_t stream)
{
    const float* x_in   = (const float*)d_in[0];
    const float* sn_g   = (const float*)d_in[1];
    const float* q_w    = (const float*)d_in[2];
    const float* kv_w   = (const float*)d_in[3];
    const float* ao_w   = (const float*)d_in[4];
    const float* sgn_g  = (const float*)d_in[5];
    const float* sg_grow   = (const float*)d_in[6];
    const float* sg_shrink = (const float*)d_in[7];
    const float* hn_g   = (const float*)d_in[8];
    const float* h_in_w = (const float*)d_in[9];
    const float* h_conv_w = (const float*)d_in[10];
    const float* h_conv_b = (const float*)d_in[11];
    const float* h_gates_w = (const float*)d_in[12];
    const float* h_gates_b = (const float*)d_in[13];
    const float* h_forget  = (const float*)d_in[14];
    const float* h_out_w   = (const float*)d_in[15];
    const float* hgn_g  = (const float*)d_in[16];
    const float* hg_grow   = (const float*)d_in[17];
    const float* hg_shrink = (const float*)d_in[18];
    float* out = (float*)d_out;

    float* R1 = (float*)d_ws;
    float* R2 = R1 + 25165824;
    float* R4 = R1 + 50331648;

    const long M = (long)B_ * T_;   // 8192
    dim3 blk(256);
    const float* NUL = nullptr;

    // ---- attention sublayer ----
    float* XN = R2;
    float* Q  = R1;
    float* KV = R1 + 8388608;
    float* AT = R1 + 10485760;
    rmsnorm_kernel<<<dim3(M), blk, 0, stream>>>(x_in, sn_g, XN);
    gemm_kernel<0><<<dim3(8, 64), blk, 0, stream>>>(XN, q_w, NUL, NUL, NUL, NUL, NUL, nullptr, Q, M, 1024, 1024);
    gemm_kernel<0><<<dim3(2, 64), blk, 0, stream>>>(XN, kv_w, NUL, NUL, NUL, NUL, NUL, nullptr, KV, M, 256, 1024);
    rope_kernel<<<dim3(cdivl((long)B_ * T_ * (HQ_ + 1) * 64, 256)), blk, 0, stream>>>(Q, KV);
    attn_kernel<<<dim3(T_ / 64, HQ_, B_), blk, 0, stream>>>(Q, KV, AT);
    gemm_kernel<2><<<dim3(8, 64), blk, 0, stream>>>(AT, ao_w, NUL, x_in, NUL, NUL, NUL, nullptr, out, M, 1024, 1024);

    // ---- MLP 1 ----
    {
        float* GATE = R1;             // [8192,2048]
        rmsnorm_kernel<<<dim3(M), blk, 0, stream>>>(out, sgn_g, XN);
        gemm_kernel<0><<<dim3(16, 64), blk, 0, stream>>>(XN, sg_grow, NUL, NUL, NUL, NUL, NUL, nullptr, GATE, M, 2048, 1024);
        gemm_kernel<3><<<dim3(16, 64), blk, 0, stream>>>(XN, sg_grow + (size_t)2048 * 1024, NUL, NUL, GATE, NUL, NUL, nullptr, GATE, M, 2048, 1024);
        gemm_kernel<2><<<dim3(8, 64), blk, 0, stream>>>(GATE, sg_shrink, NUL, out, NUL, NUL, NUL, nullptr, out, M, 1024, 2048);
    }

    // ---- hawk ----
    {
        float* GATE = R1;             // [8192,1536]
        float* U    = R1 + 12582912;  // [8192,1536] -> later FG/ALPHA
        float* XC   = R2;             // [8192,1536] (XN dead by then)
        float* XIN  = R2 + 12582912;  // [8192,1536]
        float* PB = R4, *LB = R4 + 196608, *IB = R4 + 393216;
        rmsnorm_kernel<<<dim3(M), blk, 0, stream>>>(out, hn_g, XN);
        gemm_kernel<0><<<dim3(12, 64), blk, 0, stream>>>(XN, h_in_w, NUL, NUL, NUL, NUL, NUL, nullptr, GATE, M, 1536, 1024);
        gemm_kernel<0><<<dim3(12, 64), blk, 0, stream>>>(XN, h_in_w + (size_t)1536 * 1024, NUL, NUL, NUL, NUL, NUL, nullptr, U, M, 1536, 1024);
        conv_kernel<<<dim3(cdivl(M * HH_, 256)), blk, 0, stream>>>(U, h_conv_w, h_conv_b, XC);
        // FG (over U region), then IG with fused gatex epilogue
        gemm_kernel<1><<<dim3(12, 64), blk, 0, stream>>>(XC, h_gates_w, h_gates_b, NUL, NUL, NUL, NUL, nullptr, U, M, 1536, 1536);
        gemm_kernel<4><<<dim3(12, 64), blk, 0, stream>>>(XC, h_gates_w + (size_t)1536 * 1536, h_gates_b + 1536, NUL, U, XC, h_forget, U, XIN, M, 1536, 1536);
        scan1_kernel<<<dim3(cdivl((long)B_ * NC_ * HH_, 256)), blk, 0, stream>>>(U, XIN, PB, LB);
        scan2_kernel<<<dim3(cdivl((long)B_ * HH_, 256)), blk, 0, stream>>>(PB, LB, IB);
        scan3_kernel<<<dim3(cdivl((long)B_ * NC_ * HH_, 256)), blk, 0, stream>>>(U, IB, XIN);
        glu_kernel<<<dim3(cdivl(M * (HH_ / 4), 256)), blk, 0, stream>>>(GATE, XIN, XIN, HH_, HH_, HH_, HH_ / 4, M);
        gemm_kernel<2><<<dim3(8, 64), blk, 0, stream>>>(XIN, h_out_w, NUL, out, NUL, NUL, NUL, nullptr, out, M, 1024, 1536);
    }

    // ---- MLP 2 ----
    {
        float* GATE = R1;             // [8192,2048]
        rmsnorm_kernel<<<dim3(M), blk, 0, stream>>>(out, hgn_g, XN);
        gemm_kernel<0><<<dim3(16, 64), blk, 0, stream>>>(XN, hg_grow, NUL, NUL, NUL, NUL, NUL, nullptr, GATE, M, 2048, 1024);
        gemm_kernel<3><<<dim3(16, 64), blk, 0, stream>>>(XN, hg_grow + (size_t)2048 * 1024, NUL, NUL, GATE, NUL, NUL, nullptr, GATE, M, 2048, 1024);
        gemm_kernel<2><<<dim3(8, 64), blk, 0, stream>>>(GATE, hg_shrink, NUL, out, NUL, NUL, NUL, nullptr, out, M, 1024, 2048);
    }
}

// Round 4
// 1764.990 us; speedup vs baseline: 1.5336x; 1.5336x over previous
//
#include <hip/hip_runtime.h>
#include <hip/hip_bf16.h>
#include <math.h>

#define B_  2
#define T_  4096
#define D_  1024
#define HD_ 128
#define HQ_ 8
#define W_  1024
#define HH_ 1536
#define HG_ 2048
#define KC_ 4

typedef float  f32x4  __attribute__((ext_vector_type(4)));
typedef float  f32x2  __attribute__((ext_vector_type(2)));
typedef __bf16 bf16x8 __attribute__((ext_vector_type(8)));
typedef unsigned short u16x4 __attribute__((ext_vector_type(4)));

__device__ __forceinline__ unsigned short f2bf(float f) {
    unsigned int u = __builtin_bit_cast(unsigned int, f);
    u += 0x7fffu + ((u >> 16) & 1u);           // round-to-nearest-even
    return (unsigned short)(u >> 16);
}
__device__ __forceinline__ float gelu_exact(float x) {
    return 0.5f * x * (1.0f + erff(x * 0.70710678118654752f));
}
__device__ __forceinline__ float sigmoidf_(float x) {
    return 1.0f / (1.0f + expf(-x));
}
__device__ __forceinline__ bf16x8 pack8(const float* p) {
    f32x4 a = *(const f32x4*)p;
    f32x4 b = *(const f32x4*)(p + 4);
    union { bf16x8 v; unsigned short s[8]; } u;
    u.s[0] = f2bf(a.x); u.s[1] = f2bf(a.y); u.s[2] = f2bf(a.z); u.s[3] = f2bf(a.w);
    u.s[4] = f2bf(b.x); u.s[5] = f2bf(b.y); u.s[6] = f2bf(b.z); u.s[7] = f2bf(b.w);
    return u.v;
}

// ---------------------------------------------------------------------------
// GEMM: out[M][N] = X[M][K] @ W[N][K]^T with fused epilogues.
// EPI: 0 none | 1 +bias | 2 +res | 3 glu: out=gelu(gatebuf)*acc (gatebuf==out)
//      4 gatex: ig=acc+bias; fg=gatebuf; alpha=exp(-8*softplus(fb)*sig(fg));
//               alphaout=alpha (==gatebuf); out=sqrt(1-a^2+1e-6)*sig(ig)*xc
// ---------------------------------------------------------------------------
#define LPAD 40
template<int EPI>
__global__ __launch_bounds__(256)
void gemm_kernel(const float* __restrict__ X, const float* __restrict__ Wt,
                 const float* __restrict__ bias, const float* res,
                 const float* gatebuf, const float* __restrict__ xc,
                 const float* __restrict__ fb, float* alphaout,
                 float* out, int M, int N, int K)
{
    __shared__ unsigned short lA[128 * LPAD];
    __shared__ unsigned short lB[128 * LPAD];

    const int n0 = blockIdx.x * 128;
    const int m0 = blockIdx.y * 128;
    const int tid = threadIdx.x;
    const int w = tid >> 6, l = tid & 63;
    const int wr = w >> 1, wc = w & 1;
    const int lr = l & 15, lg = l >> 4;

    f32x4 acc[4][4];
#pragma unroll
    for (int i = 0; i < 4; i++)
#pragma unroll
        for (int j = 0; j < 4; j++) acc[i][j] = {0.f, 0.f, 0.f, 0.f};

    const int trow = tid >> 3;            // 0..31
    const int tcol = (tid & 7) * 4;       // 0,4,..28
    const float* Xp = X + (long)(m0 + trow) * K + tcol;
    const float* Wp = Wt + (long)(n0 + trow) * K + tcol;
    unsigned short* law = &lA[trow * LPAD + tcol];
    unsigned short* lbw = &lB[trow * LPAD + tcol];

    for (int kk = 0; kk < K; kk += 32) {
        __syncthreads();
#pragma unroll
        for (int r = 0; r < 4; r++) {
            f32x4 a = *(const f32x4*)(Xp + (long)(r * 32) * K + kk);
            f32x4 b = *(const f32x4*)(Wp + (long)(r * 32) * K + kk);
            u16x4 av, bv;
            av.x = f2bf(a.x); av.y = f2bf(a.y); av.z = f2bf(a.z); av.w = f2bf(a.w);
            bv.x = f2bf(b.x); bv.y = f2bf(b.y); bv.z = f2bf(b.z); bv.w = f2bf(b.w);
            *(u16x4*)(law + r * 32 * LPAD) = av;
            *(u16x4*)(lbw + r * 32 * LPAD) = bv;
        }
        __syncthreads();

        bf16x8 afr[4], bfr[4];
#pragma unroll
        for (int m = 0; m < 4; m++)
            afr[m] = *(const bf16x8*)&lA[(wr * 64 + m * 16 + lr) * LPAD + lg * 8];
#pragma unroll
        for (int n = 0; n < 4; n++)
            bfr[n] = *(const bf16x8*)&lB[(wc * 64 + n * 16 + lr) * LPAD + lg * 8];
#pragma unroll
        for (int m = 0; m < 4; m++)
#pragma unroll
            for (int n = 0; n < 4; n++)
                acc[m][n] = __builtin_amdgcn_mfma_f32_16x16x32_bf16(afr[m], bfr[n], acc[m][n], 0, 0, 0);
    }

#pragma unroll
    for (int m = 0; m < 4; m++)
#pragma unroll
        for (int n = 0; n < 4; n++) {
            const int col = n0 + wc * 64 + n * 16 + lr;
            float bv = (EPI == 1 || EPI == 4) ? bias[col] : 0.f;
            float spv = 0.f;
            if (EPI == 4) {
                float f = fb[col];
                spv = (f > 20.f) ? f : log1pf(expf(f));
            }
#pragma unroll
            for (int r = 0; r < 4; r++) {
                const int row = m0 + wr * 64 + m * 16 + lg * 4 + r;
                const long idx = (long)row * N + col;
                float v = acc[m][n][r] + bv;
                if (EPI == 2) v += res[idx];
                if (EPI == 3) v = gelu_exact(gatebuf[idx]) * v;
                if (EPI == 4) {
                    float fg = gatebuf[idx];
                    float a = expf(-8.0f * spv * sigmoidf_(fg));
                    alphaout[idx] = a;
                    v = sqrtf(1.f - a * a + 1e-6f) * sigmoidf_(v) * xc[idx];
                }
                out[idx] = v;
            }
        }
}

// ---------------------------------------------------------------------------
// RMSNorm
// ---------------------------------------------------------------------------
__global__ __launch_bounds__(256)
void rmsnorm_kernel(const float* __restrict__ x, const float* __restrict__ g,
                    float* __restrict__ out)
{
    const long row = blockIdx.x;
    const int tid = threadIdx.x;
    const float* xp = x + row * D_;
    f32x4 v = *(const f32x4*)(xp + tid * 4);
    float ss = v.x * v.x + v.y * v.y + v.z * v.z + v.w * v.w;
#pragma unroll
    for (int o = 1; o < 64; o <<= 1) ss += __shfl_xor(ss, o);
    __shared__ float ps[4];
    if ((tid & 63) == 0) ps[tid >> 6] = ss;
    __syncthreads();
    float tot = ps[0] + ps[1] + ps[2] + ps[3];
    float inv = rsqrtf(tot) * 32.0f;     // sqrt(1024)=32
    f32x4 gv = *(const f32x4*)(g + tid * 4);
    f32x4 o4;
    o4.x = gv.x * v.x * inv; o4.y = gv.y * v.y * inv;
    o4.z = gv.z * v.z * inv; o4.w = gv.w * v.w * inv;
    *(f32x4*)(out + row * D_ + tid * 4) = o4;
}

// ---------------------------------------------------------------------------
// RoPE (in-place on q and the k half of kv)
// ---------------------------------------------------------------------------
__global__ void rope_kernel(float* __restrict__ q, float* __restrict__ kv)
{
    const long NQ = (long)B_ * T_ * HQ_ * 64;
    const long NK = (long)B_ * T_ * 64;
    long idx = (long)blockIdx.x * blockDim.x + threadIdx.x;
    if (idx >= NQ + NK) return;
    int i; long t; float* ptr;
    if (idx < NQ) {
        i = idx & 63;
        long bth = idx >> 6;
        t = (bth / HQ_) % T_;
        ptr = q + bth * HD_ + 2 * i;
    } else {
        long k = idx - NQ;
        i = k & 63;
        long bt = k >> 6;
        t = bt % T_;
        ptr = kv + bt * (2 * HD_) + 2 * i;
    }
    float freq = exp2f(-(float)i * 0.20762050593046014f);  // log2(1e4)/64
    float ang = (float)t * freq;
    float sn, cs;
    sincosf(ang, &sn, &cs);
    f32x2 xv = *(f32x2*)ptr;
    f32x2 yv;
    yv.x = xv.x * cs - xv.y * sn;
    yv.y = xv.x * sn + xv.y * cs;
    *(f32x2*)ptr = yv;
}

// ---------------------------------------------------------------------------
// MFMA sliding-window attention.
// Block: 64 queries x (head,b). 4 waves x 16 queries. Tiles of 64 keys.
// K_lds [64key][136], Vt_lds [128d][72] (transposed), P per-wave [16][72].
// Fragment mapping (validated by gemm_kernel): A row=lr k=lg*8+j;
// B(^T) col-row=lr k=lg*8+j; C/D row=lg*4+r col=lr.
// ---------------------------------------------------------------------------
#define KLD 136
#define VLD 72
#define PLD 72

__global__ __launch_bounds__(256)
void attn_mfma_kernel(const float* __restrict__ q, const float* __restrict__ kv,
                      float* __restrict__ o)
{
    __shared__ unsigned short Ksh[64 * KLD];
    __shared__ unsigned short Vsh[128 * VLD];
    __shared__ unsigned short Psh[4 * 16 * PLD];

    const int qt = blockIdx.x, h = blockIdx.y, b = blockIdx.z;
    const int q0 = qt * 64;
    const int tid = threadIdx.x;
    const int w = tid >> 6, l = tid & 63;
    const int lr = l & 15, lg = l >> 4;

    // Q fragments (A operand): row=lr -> query q0+w*16+lr
    bf16x8 qfr[4];
    {
        const float* qp = q + (((long)b * T_ + q0 + w * 16 + lr) * HQ_ + h) * HD_;
#pragma unroll
        for (int kt = 0; kt < 4; kt++) qfr[kt] = pack8(qp + kt * 32 + lg * 8);
    }

    f32x4 oacc[8];
#pragma unroll
    for (int dt = 0; dt < 8; dt++) oacc[dt] = {0.f, 0.f, 0.f, 0.f};
    float mrun[4], srun[4];
#pragma unroll
    for (int r = 0; r < 4; r++) { mrun[r] = -1e30f; srun[r] = 0.f; }

    const int kt_lo = (q0 >= W_) ? (q0 - W_) : 0;
    const int skr = tid >> 2;            // K staging row 0..63
    const int skd = (tid & 3) * 32;      // K staging d-block
    const int svk = l;                   // V staging key = lane
    const int svd = w * 32;              // V staging d-slab per wave

    for (int kt0 = kt_lo; kt0 <= q0; kt0 += 64) {
        __syncthreads();
        {   // stage K -> Ksh[key][d] (bf16)
            const float* kp = kv + (((long)b * T_ + kt0 + skr) * 2) * HD_ + skd;
            unsigned short* dst = &Ksh[skr * KLD + skd];
#pragma unroll
            for (int rr = 0; rr < 8; rr++) {
                f32x4 a = *(const f32x4*)(kp + rr * 4);
                u16x4 c;
                c.x = f2bf(a.x); c.y = f2bf(a.y); c.z = f2bf(a.z); c.w = f2bf(a.w);
                *(u16x4*)(dst + rr * 4) = c;
            }
        }
        {   // stage V transposed -> Vsh[d][key] (bf16)
            const float* vp = kv + (((long)b * T_ + kt0 + svk) * 2 + 1) * HD_ + svd;
#pragma unroll
            for (int rr = 0; rr < 8; rr++) {
                f32x4 a = *(const f32x4*)(vp + rr * 4);
                Vsh[(svd + rr * 4 + 0) * VLD + svk] = f2bf(a.x);
                Vsh[(svd + rr * 4 + 1) * VLD + svk] = f2bf(a.y);
                Vsh[(svd + rr * 4 + 2) * VLD + svk] = f2bf(a.z);
                Vsh[(svd + rr * 4 + 3) * VLD + svk] = f2bf(a.w);
            }
        }
        __syncthreads();

        // QK^T: s[ct] covers keys ct*16+lr, rows lg*4+r
        f32x4 s[4];
#pragma unroll
        for (int ct = 0; ct < 4; ct++) {
            s[ct] = {0.f, 0.f, 0.f, 0.f};
#pragma unroll
            for (int kt = 0; kt < 4; kt++) {
                bf16x8 kf = *(const bf16x8*)&Ksh[(ct * 16 + lr) * KLD + kt * 32 + lg * 8];
                s[ct] = __builtin_amdgcn_mfma_f32_16x16x32_bf16(qfr[kt], kf, s[ct], 0, 0, 0);
            }
        }

        // scale + window mask + tile max
        float tmax[4] = {-3e38f, -3e38f, -3e38f, -3e38f};
#pragma unroll
        for (int ct = 0; ct < 4; ct++) {
            const int kpos = kt0 + ct * 16 + lr;
#pragma unroll
            for (int r = 0; r < 4; r++) {
                const int qpos = q0 + w * 16 + lg * 4 + r;
                float v = s[ct][r] * 0.08838834764831845f;
                bool valid = (kpos <= qpos) && (kpos + W_ >= qpos);
                v = valid ? v : -3e38f;
                s[ct][r] = v;
                tmax[r] = fmaxf(tmax[r], v);
            }
        }
#pragma unroll
        for (int r = 0; r < 4; r++)
#pragma unroll
            for (int msk = 1; msk < 16; msk <<= 1)
                tmax[r] = fmaxf(tmax[r], __shfl_xor(tmax[r], msk));

        float fr[4], psum[4];
#pragma unroll
        for (int r = 0; r < 4; r++) {
            float mnew = fmaxf(mrun[r], tmax[r]);
            fr[r] = __expf(mrun[r] - mnew);
            mrun[r] = mnew;
            srun[r] *= fr[r];
            psum[r] = 0.f;
        }
#pragma unroll
        for (int dt = 0; dt < 8; dt++) {
            oacc[dt][0] *= fr[0]; oacc[dt][1] *= fr[1];
            oacc[dt][2] *= fr[2]; oacc[dt][3] *= fr[3];
        }

        unsigned short* pw = &Psh[w * 16 * PLD];
#pragma unroll
        for (int ct = 0; ct < 4; ct++)
#pragma unroll
            for (int r = 0; r < 4; r++) {
                float p = __expf(s[ct][r] - mrun[r]);
                psum[r] += p;
                pw[(lg * 4 + r) * PLD + ct * 16 + lr] = f2bf(p);
            }
#pragma unroll
        for (int r = 0; r < 4; r++) {
#pragma unroll
            for (int msk = 1; msk < 16; msk <<= 1)
                psum[r] += __shfl_xor(psum[r], msk);
            srun[r] += psum[r];
        }

        asm volatile("s_waitcnt lgkmcnt(0)" ::: "memory");
        bf16x8 pa0 = *(const bf16x8*)&pw[lr * PLD + lg * 8];
        bf16x8 pa1 = *(const bf16x8*)&pw[lr * PLD + 32 + lg * 8];
#pragma unroll
        for (int dt = 0; dt < 8; dt++) {
            bf16x8 vf0 = *(const bf16x8*)&Vsh[(dt * 16 + lr) * VLD + lg * 8];
            bf16x8 vf1 = *(const bf16x8*)&Vsh[(dt * 16 + lr) * VLD + 32 + lg * 8];
            oacc[dt] = __builtin_amdgcn_mfma_f32_16x16x32_bf16(pa0, vf0, oacc[dt], 0, 0, 0);
            oacc[dt] = __builtin_amdgcn_mfma_f32_16x16x32_bf16(pa1, vf1, oacc[dt], 0, 0, 0);
        }
    }

#pragma unroll
    for (int r = 0; r < 4; r++) {
        const int qpos = q0 + w * 16 + lg * 4 + r;
        float inv = 1.f / srun[r];
        float* op = o + ((long)b * T_ + qpos) * (HQ_ * HD_) + h * HD_;
#pragma unroll
        for (int dt = 0; dt < 8; dt++)
            op[dt * 16 + lr] = oacc[dt][r] * inv;
    }
}

// ---------------------------------------------------------------------------
// GLU
// ---------------------------------------------------------------------------
__global__ void glu_kernel(const float* __restrict__ gate, const float* h,
                           float* out, int gs, int hs, int os,
                           int cols4, long nrows)
{
    long idx = (long)blockIdx.x * blockDim.x + threadIdx.x;
    long total = nrows * cols4;
    if (idx >= total) return;
    long r = idx / cols4;
    int c = (int)(idx % cols4) * 4;
    f32x4 gv = *(const f32x4*)(gate + r * gs + c);
    f32x4 hv = *(const f32x4*)(h + r * hs + c);
    f32x4 o4;
    o4.x = gelu_exact(gv.x) * hv.x;
    o4.y = gelu_exact(gv.y) * hv.y;
    o4.z = gelu_exact(gv.z) * hv.z;
    o4.w = gelu_exact(gv.w) * hv.w;
    *(f32x4*)(out + r * os + c) = o4;
}

// ---------------------------------------------------------------------------
// Depthwise causal conv K=4 over u [8192,1536]
// ---------------------------------------------------------------------------
__global__ void conv_kernel(const float* __restrict__ u, const float* __restrict__ w,
                            const float* __restrict__ bias, float* __restrict__ xc)
{
    long idx = (long)blockIdx.x * blockDim.x + threadIdx.x;
    if (idx >= (long)B_ * T_ * HH_) return;
    int ch = (int)(idx % HH_);
    long row = idx / HH_;
    int t = (int)(row % T_);
    float acc = bias[ch];
#pragma unroll
    for (int k = 0; k < KC_; k++) {
        int ts = t - 3 + k;
        if (ts >= 0) acc += u[(row - t + ts) * HH_ + ch] * w[ch * KC_ + k];
    }
    xc[row * HH_ + ch] = acc;
}

// ---------------------------------------------------------------------------
// Chunked scan
// ---------------------------------------------------------------------------
#define CS_ 64
#define NC_ (T_ / CS_)
__global__ void scan1_kernel(const float* __restrict__ alpha, const float* __restrict__ xin,
                             float* __restrict__ P, float* __restrict__ L)
{
    long idx = (long)blockIdx.x * blockDim.x + threadIdx.x;
    if (idx >= (long)B_ * NC_ * HH_) return;
    int ch = (int)(idx % HH_);
    int chunk = (int)((idx / HH_) % NC_);
    int b = (int)(idx / ((long)HH_ * NC_));
    long base = ((long)b * T_ + chunk * CS_) * HH_ + ch;
    float p = 1.f, l = 0.f;
    for (int i = 0; i < CS_; i++) {
        float a = alpha[base + (long)i * HH_];
        float x = xin[base + (long)i * HH_];
        l = a * l + x;
        p *= a;
    }
    P[idx] = p; L[idx] = l;
}
__global__ void scan2_kernel(const float* __restrict__ P, const float* __restrict__ L,
                             float* __restrict__ I)
{
    long idx = (long)blockIdx.x * blockDim.x + threadIdx.x;
    if (idx >= (long)B_ * HH_) return;
    int ch = (int)(idx % HH_);
    int b = (int)(idx / HH_);
    float init = 0.f;
    for (int c = 0; c < NC_; c++) {
        long o = ((long)b * NC_ + c) * HH_ + ch;
        I[o] = init;
        init = P[o] * init + L[o];
    }
}
__global__ void scan3_kernel(const float* __restrict__ alpha, const float* __restrict__ I,
                             float* __restrict__ xin)
{
    long idx = (long)blockIdx.x * blockDim.x + threadIdx.x;
    if (idx >= (long)B_ * NC_ * HH_) return;
    int ch = (int)(idx % HH_);
    int chunk = (int)((idx / HH_) % NC_);
    int b = (int)(idx / ((long)HH_ * NC_));
    long base = ((long)b * T_ + chunk * CS_) * HH_ + ch;
    float hcur = I[idx];
    for (int i = 0; i < CS_; i++) {
        long o = base + (long)i * HH_;
        hcur = alpha[o] * hcur + xin[o];
        xin[o] = hcur;
    }
}

// ---------------------------------------------------------------------------
// launch
// ---------------------------------------------------------------------------
static inline long cdivl(long a, long b) { return (a + b - 1) / b; }

extern "C" void kernel_launch(void* const* d_in, const int* in_sizes, int n_in,
                              void* d_out, int out_size, void* d_ws, size_t ws_size,
                              hipStream_t stream)
{
    const float* x_in   = (const float*)d_in[0];
    const float* sn_g   = (const float*)d_in[1];
    const float* q_w    = (const float*)d_in[2];
    const float* kv_w   = (const float*)d_in[3];
    const float* ao_w   = (const float*)d_in[4];
    const float* sgn_g  = (const float*)d_in[5];
    const float* sg_grow   = (const float*)d_in[6];
    const float* sg_shrink = (const float*)d_in[7];
    const float* hn_g   = (const float*)d_in[8];
    const float* h_in_w = (const float*)d_in[9];
    const float* h_conv_w = (const float*)d_in[10];
    const float* h_conv_b = (const float*)d_in[11];
    const float* h_gates_w = (const float*)d_in[12];
    const float* h_gates_b = (const float*)d_in[13];
    const float* h_forget  = (const float*)d_in[14];
    const float* h_out_w   = (const float*)d_in[15];
    const float* hgn_g  = (const float*)d_in[16];
    const float* hg_grow   = (const float*)d_in[17];
    const float* hg_shrink = (const float*)d_in[18];
    float* out = (float*)d_out;

    float* R1 = (float*)d_ws;
    float* R2 = R1 + 25165824;
    float* R4 = R1 + 50331648;

    const long M = (long)B_ * T_;   // 8192
    dim3 blk(256);
    const float* NUL = nullptr;

    // ---- attention sublayer ----
    float* XN = R2;
    float* Q  = R1;
    float* KV = R1 + 8388608;
    float* AT = R1 + 10485760;
    rmsnorm_kernel<<<dim3(M), blk, 0, stream>>>(x_in, sn_g, XN);
    gemm_kernel<0><<<dim3(8, 64), blk, 0, stream>>>(XN, q_w, NUL, NUL, NUL, NUL, NUL, nullptr, Q, M, 1024, 1024);
    gemm_kernel<0><<<dim3(2, 64), blk, 0, stream>>>(XN, kv_w, NUL, NUL, NUL, NUL, NUL, nullptr, KV, M, 256, 1024);
    rope_kernel<<<dim3(cdivl((long)B_ * T_ * (HQ_ + 1) * 64, 256)), blk, 0, stream>>>(Q, KV);
    attn_mfma_kernel<<<dim3(T_ / 64, HQ_, B_), blk, 0, stream>>>(Q, KV, AT);
    gemm_kernel<2><<<dim3(8, 64), blk, 0, stream>>>(AT, ao_w, NUL, x_in, NUL, NUL, NUL, nullptr, out, M, 1024, 1024);

    // ---- MLP 1 ----
    {
        float* GATE = R1;             // [8192,2048]
        rmsnorm_kernel<<<dim3(M), blk, 0, stream>>>(out, sgn_g, XN);
        gemm_kernel<0><<<dim3(16, 64), blk, 0, stream>>>(XN, sg_grow, NUL, NUL, NUL, NUL, NUL, nullptr, GATE, M, 2048, 1024);
        gemm_kernel<3><<<dim3(16, 64), blk, 0, stream>>>(XN, sg_grow + (size_t)2048 * 1024, NUL, NUL, GATE, NUL, NUL, nullptr, GATE, M, 2048, 1024);
        gemm_kernel<2><<<dim3(8, 64), blk, 0, stream>>>(GATE, sg_shrink, NUL, out, NUL, NUL, NUL, nullptr, out, M, 1024, 2048);
    }

    // ---- hawk ----
    {
        float* GATE = R1;             // [8192,1536]
        float* U    = R1 + 12582912;  // [8192,1536] -> later FG/ALPHA
        float* XC   = R2;             // [8192,1536]
        float* XIN  = R2 + 12582912;  // [8192,1536]
        float* PB = R4, *LB = R4 + 196608, *IB = R4 + 393216;
        rmsnorm_kernel<<<dim3(M), blk, 0, stream>>>(out, hn_g, XN);
        gemm_kernel<0><<<dim3(12, 64), blk, 0, stream>>>(XN, h_in_w, NUL, NUL, NUL, NUL, NUL, nullptr, GATE, M, 1536, 1024);
        gemm_kernel<0><<<dim3(12, 64), blk, 0, stream>>>(XN, h_in_w + (size_t)1536 * 1024, NUL, NUL, NUL, NUL, NUL, nullptr, U, M, 1536, 1024);
        conv_kernel<<<dim3(cdivl(M * HH_, 256)), blk, 0, stream>>>(U, h_conv_w, h_conv_b, XC);
        gemm_kernel<1><<<dim3(12, 64), blk, 0, stream>>>(XC, h_gates_w, h_gates_b, NUL, NUL, NUL, NUL, nullptr, U, M, 1536, 1536);
        gemm_kernel<4><<<dim3(12, 64), blk, 0, stream>>>(XC, h_gates_w + (size_t)1536 * 1536, h_gates_b + 1536, NUL, U, XC, h_forget, U, XIN, M, 1536, 1536);
        scan1_kernel<<<dim3(cdivl((long)B_ * NC_ * HH_, 256)), blk, 0, stream>>>(U, XIN, PB, LB);
        scan2_kernel<<<dim3(cdivl((long)B_ * HH_, 256)), blk, 0, stream>>>(PB, LB, IB);
        scan3_kernel<<<dim3(cdivl((long)B_ * NC_ * HH_, 256)), blk, 0, stream>>>(U, IB, XIN);
        glu_kernel<<<dim3(cdivl(M * (HH_ / 4), 256)), blk, 0, stream>>>(GATE, XIN, XIN, HH_, HH_, HH_, HH_ / 4, M);
        gemm_kernel<2><<<dim3(8, 64), blk, 0, stream>>>(XIN, h_out_w, NUL, out, NUL, NUL, NUL, nullptr, out, M, 1024, 1536);
    }

    // ---- MLP 2 ----
    {
        float* GATE = R1;             // [8192,2048]
        rmsnorm_kernel<<<dim3(M), blk, 0, stream>>>(out, hgn_g, XN);
        gemm_kernel<0><<<dim3(16, 64), blk, 0, stream>>>(XN, hg_grow, NUL, NUL, NUL, NUL, NUL, nullptr, GATE, M, 2048, 1024);
        gemm_kernel<3><<<dim3(16, 64), blk, 0, stream>>>(XN, hg_grow + (size_t)2048 * 1024, NUL, NUL, GATE, NUL, NUL, nullptr, GATE, M, 2048, 1024);
        gemm_kernel<2><<<dim3(8, 64), blk, 0, stream>>>(GATE, hg_shrink, NUL, out, NUL, NUL, NUL, nullptr, out, M, 1024, 2048);
    }
}

// Round 5
// 1259.576 us; speedup vs baseline: 2.1490x; 1.4013x over previous
//
#include <hip/hip_runtime.h>
#include <hip/hip_bf16.h>
#include <math.h>

#define B_  2
#define T_  4096
#define D_  1024
#define HD_ 128
#define HQ_ 8
#define W_  1024
#define HH_ 1536
#define HG_ 2048
#define KC_ 4

typedef float  f32x4  __attribute__((ext_vector_type(4)));
typedef float  f32x2  __attribute__((ext_vector_type(2)));
typedef __bf16 bf16x8 __attribute__((ext_vector_type(8)));
typedef unsigned short u16;
typedef unsigned short u16x4 __attribute__((ext_vector_type(4)));

__device__ __forceinline__ u16 f2bf(float f) {
    unsigned int u = __builtin_bit_cast(unsigned int, f);
    u += 0x7fffu + ((u >> 16) & 1u);           // RNE
    return (u16)(u >> 16);
}
__device__ __forceinline__ float bf2f(u16 v) {
    unsigned int u = ((unsigned int)v) << 16;
    return __builtin_bit_cast(float, u);
}
__device__ __forceinline__ float gelu_exact(float x) {
    return 0.5f * x * (1.0f + erff(x * 0.70710678118654752f));
}
__device__ __forceinline__ float sigmoidf_(float x) {
    return 1.0f / (1.0f + expf(-x));
}
__device__ __forceinline__ bf16x8 pack8(const float* p) {
    f32x4 a = *(const f32x4*)p;
    f32x4 b = *(const f32x4*)(p + 4);
    union { bf16x8 v; u16 s[8]; } u;
    u.s[0] = f2bf(a.x); u.s[1] = f2bf(a.y); u.s[2] = f2bf(a.z); u.s[3] = f2bf(a.w);
    u.s[4] = f2bf(b.x); u.s[5] = f2bf(b.y); u.s[6] = f2bf(b.z); u.s[7] = f2bf(b.w);
    return u.v;
}

#define GLOAD16(gp, lp) __builtin_amdgcn_global_load_lds( \
    (const __attribute__((address_space(1))) void*)(gp),  \
    (__attribute__((address_space(3))) void*)(lp), 16, 0, 0)

// ---------------------------------------------------------------------------
// f32 -> bf16 conversion (weights)
// ---------------------------------------------------------------------------
__global__ void cvt_kernel(const float* __restrict__ src, u16* __restrict__ dst, long n)
{
    long i = ((long)blockIdx.x * blockDim.x + threadIdx.x) * 8;
    if (i >= n) return;
    f32x4 a = *(const f32x4*)(src + i);
    f32x4 b = *(const f32x4*)(src + i + 4);
    u16x4 ua, ub;
    ua.x = f2bf(a.x); ua.y = f2bf(a.y); ua.z = f2bf(a.z); ua.w = f2bf(a.w);
    ub.x = f2bf(b.x); ub.y = f2bf(b.y); ub.z = f2bf(b.z); ub.w = f2bf(b.w);
    *(u16x4*)(dst + i) = ua;
    *(u16x4*)(dst + i + 4) = ub;
}

// ---------------------------------------------------------------------------
// bf16 GEMM (m97 structure): out[M][N] = A[M][K] @ B[N][K]^T, A/B bf16.
// 128x128 tile, BK=64, global_load_lds(16B) into linear LDS, 2 barriers/K-step.
// EPI: 0 none | 1 +bias | 2 +res(f32) | 3 glu: out=gelu(gatebuf)*acc
// OBF: write bf16 (u16) else f32.
// ---------------------------------------------------------------------------
template<int EPI, bool OBF>
__global__ __launch_bounds__(256)
void gemm_bf16_kernel(const u16* __restrict__ A, const u16* __restrict__ Bw,
                      const float* __restrict__ bias, const float* __restrict__ res,
                      const u16* gatebuf, void* outv,
                      int M, int N, int K)
{
    __shared__ u16 lA[128 * 64];
    __shared__ u16 lB[128 * 64];
    const int n0 = blockIdx.x * 128, m0 = blockIdx.y * 128;
    const int tid = threadIdx.x, w = tid >> 6, l = tid & 63;
    const int wr = w >> 1, wc = w & 1, lr = l & 15, lg = l >> 4;

    f32x4 acc[4][4];
#pragma unroll
    for (int i = 0; i < 4; i++)
#pragma unroll
        for (int j = 0; j < 4; j++) acc[i][j] = {0.f, 0.f, 0.f, 0.f};

    // staging: wave w owns chunks w*4..w*4+3 of each tile; chunk = 8 rows x 64 el
    const int rl = l >> 3;            // row within chunk
    const int cb = (l & 7) * 8;       // col elems within row
    const u16* gA = A + (long)(m0 + w * 32 + rl) * K + cb;
    const u16* gB = Bw + (long)(n0 + w * 32 + rl) * K + cb;
    u16* lAw = &lA[w * 2048];
    u16* lBw = &lB[w * 2048];

    for (int kk = 0; kk < K; kk += 64) {
        __syncthreads();              // prior reads done before overwrite
#pragma unroll
        for (int c = 0; c < 4; c++) {
            GLOAD16(gA + (long)c * 8 * K + kk, lAw + c * 512);
            GLOAD16(gB + (long)c * 8 * K + kk, lBw + c * 512);
        }
        __syncthreads();              // staging visible (vmcnt(0) before barrier)
#pragma unroll
        for (int ks = 0; ks < 2; ks++) {
            bf16x8 af[4], bfr[4];
#pragma unroll
            for (int m = 0; m < 4; m++)
                af[m] = *(const bf16x8*)&lA[(wr * 64 + m * 16 + lr) * 64 + ks * 32 + lg * 8];
#pragma unroll
            for (int n = 0; n < 4; n++)
                bfr[n] = *(const bf16x8*)&lB[(wc * 64 + n * 16 + lr) * 64 + ks * 32 + lg * 8];
#pragma unroll
            for (int m = 0; m < 4; m++)
#pragma unroll
                for (int n = 0; n < 4; n++)
                    acc[m][n] = __builtin_amdgcn_mfma_f32_16x16x32_bf16(af[m], bfr[n], acc[m][n], 0, 0, 0);
        }
    }

#pragma unroll
    for (int m = 0; m < 4; m++)
#pragma unroll
        for (int n = 0; n < 4; n++) {
            const int col = n0 + wc * 64 + n * 16 + lr;
            const float bv = (EPI == 1) ? bias[col] : 0.f;
#pragma unroll
            for (int r = 0; r < 4; r++) {
                const int row = m0 + wr * 64 + m * 16 + lg * 4 + r;
                const long idx = (long)row * N + col;
                float v = acc[m][n][r] + bv;
                if (EPI == 2) v += res[idx];
                if (EPI == 3) v = gelu_exact(bf2f(gatebuf[idx])) * v;
                if (OBF) ((u16*)outv)[idx] = f2bf(v);
                else     ((float*)outv)[idx] = v;
            }
        }
}

// ---------------------------------------------------------------------------
// RMSNorm -> bf16
// ---------------------------------------------------------------------------
__global__ __launch_bounds__(256)
void rmsnorm_kernel(const float* __restrict__ x, const float* __restrict__ g,
                    u16* __restrict__ out)
{
    const long row = blockIdx.x;
    const int tid = threadIdx.x;
    const float* xp = x + row * D_;
    f32x4 v = *(const f32x4*)(xp + tid * 4);
    float ss = v.x * v.x + v.y * v.y + v.z * v.z + v.w * v.w;
#pragma unroll
    for (int o = 1; o < 64; o <<= 1) ss += __shfl_xor(ss, o);
    __shared__ float ps[4];
    if ((tid & 63) == 0) ps[tid >> 6] = ss;
    __syncthreads();
    float tot = ps[0] + ps[1] + ps[2] + ps[3];
    float inv = rsqrtf(tot) * 32.0f;     // sqrt(1024)=32
    f32x4 gv = *(const f32x4*)(g + tid * 4);
    u16x4 o4;
    o4.x = f2bf(gv.x * v.x * inv); o4.y = f2bf(gv.y * v.y * inv);
    o4.z = f2bf(gv.z * v.z * inv); o4.w = f2bf(gv.w * v.w * inv);
    *(u16x4*)(out + row * D_ + tid * 4) = o4;
}

// ---------------------------------------------------------------------------
// RoPE (in-place, f32 Q and K half of KV)
// ---------------------------------------------------------------------------
__global__ void rope_kernel(float* __restrict__ q, float* __restrict__ kv)
{
    const long NQ = (long)B_ * T_ * HQ_ * 64;
    const long NK = (long)B_ * T_ * 64;
    long idx = (long)blockIdx.x * blockDim.x + threadIdx.x;
    if (idx >= NQ + NK) return;
    int i; long t; float* ptr;
    if (idx < NQ) {
        i = idx & 63;
        long bth = idx >> 6;
        t = (bth / HQ_) % T_;
        ptr = q + bth * HD_ + 2 * i;
    } else {
        long k = idx - NQ;
        i = k & 63;
        long bt = k >> 6;
        t = bt % T_;
        ptr = kv + bt * (2 * HD_) + 2 * i;
    }
    float freq = exp2f(-(float)i * 0.20762050593046014f);  // log2(1e4)/64
    float ang = (float)t * freq;
    float sn, cs;
    sincosf(ang, &sn, &cs);
    f32x2 xv = *(f32x2*)ptr;
    f32x2 yv;
    yv.x = xv.x * cs - xv.y * sn;
    yv.y = xv.x * sn + xv.y * cs;
    *(f32x2*)ptr = yv;
}

// ---------------------------------------------------------------------------
// MFMA sliding-window attention (unchanged math; bf16 output)
// ---------------------------------------------------------------------------
#define KLD 136
#define VLD 72
#define PLD 72

__global__ __launch_bounds__(256)
void attn_mfma_kernel(const float* __restrict__ q, const float* __restrict__ kv,
                      u16* __restrict__ o)
{
    __shared__ u16 Ksh[64 * KLD];
    __shared__ u16 Vsh[128 * VLD];
    __shared__ u16 Psh[4 * 16 * PLD];

    const int qt = blockIdx.x, h = blockIdx.y, b = blockIdx.z;
    const int q0 = qt * 64;
    const int tid = threadIdx.x;
    const int w = tid >> 6, l = tid & 63;
    const int lr = l & 15, lg = l >> 4;

    bf16x8 qfr[4];
    {
        const float* qp = q + (((long)b * T_ + q0 + w * 16 + lr) * HQ_ + h) * HD_;
#pragma unroll
        for (int kt = 0; kt < 4; kt++) qfr[kt] = pack8(qp + kt * 32 + lg * 8);
    }

    f32x4 oacc[8];
#pragma unroll
    for (int dt = 0; dt < 8; dt++) oacc[dt] = {0.f, 0.f, 0.f, 0.f};
    float mrun[4], srun[4];
#pragma unroll
    for (int r = 0; r < 4; r++) { mrun[r] = -1e30f; srun[r] = 0.f; }

    const int kt_lo = (q0 >= W_) ? (q0 - W_) : 0;
    const int skr = tid >> 2;
    const int skd = (tid & 3) * 32;
    const int svk = l;
    const int svd = w * 32;

    for (int kt0 = kt_lo; kt0 <= q0; kt0 += 64) {
        __syncthreads();
        {
            const float* kp = kv + (((long)b * T_ + kt0 + skr) * 2) * HD_ + skd;
            u16* dst = &Ksh[skr * KLD + skd];
#pragma unroll
            for (int rr = 0; rr < 8; rr++) {
                f32x4 a = *(const f32x4*)(kp + rr * 4);
                u16x4 c;
                c.x = f2bf(a.x); c.y = f2bf(a.y); c.z = f2bf(a.z); c.w = f2bf(a.w);
                *(u16x4*)(dst + rr * 4) = c;
            }
        }
        {
            const float* vp = kv + (((long)b * T_ + kt0 + svk) * 2 + 1) * HD_ + svd;
#pragma unroll
            for (int rr = 0; rr < 8; rr++) {
                f32x4 a = *(const f32x4*)(vp + rr * 4);
                Vsh[(svd + rr * 4 + 0) * VLD + svk] = f2bf(a.x);
                Vsh[(svd + rr * 4 + 1) * VLD + svk] = f2bf(a.y);
                Vsh[(svd + rr * 4 + 2) * VLD + svk] = f2bf(a.z);
                Vsh[(svd + rr * 4 + 3) * VLD + svk] = f2bf(a.w);
            }
        }
        __syncthreads();

        f32x4 s[4];
#pragma unroll
        for (int ct = 0; ct < 4; ct++) {
            s[ct] = {0.f, 0.f, 0.f, 0.f};
#pragma unroll
            for (int kt = 0; kt < 4; kt++) {
                bf16x8 kf = *(const bf16x8*)&Ksh[(ct * 16 + lr) * KLD + kt * 32 + lg * 8];
                s[ct] = __builtin_amdgcn_mfma_f32_16x16x32_bf16(qfr[kt], kf, s[ct], 0, 0, 0);
            }
        }

        float tmax[4] = {-3e38f, -3e38f, -3e38f, -3e38f};
#pragma unroll
        for (int ct = 0; ct < 4; ct++) {
            const int kpos = kt0 + ct * 16 + lr;
#pragma unroll
            for (int r = 0; r < 4; r++) {
                const int qpos = q0 + w * 16 + lg * 4 + r;
                float v = s[ct][r] * 0.08838834764831845f;
                bool valid = (kpos <= qpos) && (kpos + W_ >= qpos);
                v = valid ? v : -3e38f;
                s[ct][r] = v;
                tmax[r] = fmaxf(tmax[r], v);
            }
        }
#pragma unroll
        for (int r = 0; r < 4; r++)
#pragma unroll
            for (int msk = 1; msk < 16; msk <<= 1)
                tmax[r] = fmaxf(tmax[r], __shfl_xor(tmax[r], msk));

        float fr[4], psum[4];
#pragma unroll
        for (int r = 0; r < 4; r++) {
            float mnew = fmaxf(mrun[r], tmax[r]);
            fr[r] = __expf(mrun[r] - mnew);
            mrun[r] = mnew;
            srun[r] *= fr[r];
            psum[r] = 0.f;
        }
#pragma unroll
        for (int dt = 0; dt < 8; dt++) {
            oacc[dt][0] *= fr[0]; oacc[dt][1] *= fr[1];
            oacc[dt][2] *= fr[2]; oacc[dt][3] *= fr[3];
        }

        u16* pw = &Psh[w * 16 * PLD];
#pragma unroll
        for (int ct = 0; ct < 4; ct++)
#pragma unroll
            for (int r = 0; r < 4; r++) {
                float p = __expf(s[ct][r] - mrun[r]);
                psum[r] += p;
                pw[(lg * 4 + r) * PLD + ct * 16 + lr] = f2bf(p);
            }
#pragma unroll
        for (int r = 0; r < 4; r++) {
#pragma unroll
            for (int msk = 1; msk < 16; msk <<= 1)
                psum[r] += __shfl_xor(psum[r], msk);
            srun[r] += psum[r];
        }

        asm volatile("s_waitcnt lgkmcnt(0)" ::: "memory");
        bf16x8 pa0 = *(const bf16x8*)&pw[lr * PLD + lg * 8];
        bf16x8 pa1 = *(const bf16x8*)&pw[lr * PLD + 32 + lg * 8];
#pragma unroll
        for (int dt = 0; dt < 8; dt++) {
            bf16x8 vf0 = *(const bf16x8*)&Vsh[(dt * 16 + lr) * VLD + lg * 8];
            bf16x8 vf1 = *(const bf16x8*)&Vsh[(dt * 16 + lr) * VLD + 32 + lg * 8];
            oacc[dt] = __builtin_amdgcn_mfma_f32_16x16x32_bf16(pa0, vf0, oacc[dt], 0, 0, 0);
            oacc[dt] = __builtin_amdgcn_mfma_f32_16x16x32_bf16(pa1, vf1, oacc[dt], 0, 0, 0);
        }
    }

#pragma unroll
    for (int r = 0; r < 4; r++) {
        const int qpos = q0 + w * 16 + lg * 4 + r;
        float inv = 1.f / srun[r];
        u16* op = o + ((long)b * T_ + qpos) * (HQ_ * HD_) + h * HD_;
#pragma unroll
        for (int dt = 0; dt < 8; dt++)
            op[dt * 16 + lr] = f2bf(oacc[dt][r] * inv);
    }
}

// ---------------------------------------------------------------------------
// Depthwise causal conv K=4 over bf16 u [8192,1536] -> bf16 xc
// ---------------------------------------------------------------------------
__global__ void conv_kernel(const u16* __restrict__ u, const float* __restrict__ w,
                            const float* __restrict__ bias, u16* __restrict__ xc)
{
    long idx = (long)blockIdx.x * blockDim.x + threadIdx.x;
    if (idx >= (long)B_ * T_ * HH_) return;
    int ch = (int)(idx % HH_);
    long row = idx / HH_;
    int t = (int)(row % T_);
    float acc = bias[ch];
#pragma unroll
    for (int k = 0; k < KC_; k++) {
        int ts = t - 3 + k;
        if (ts >= 0) acc += bf2f(u[(row - t + ts) * HH_ + ch]) * w[ch * KC_ + k];
    }
    xc[idx] = f2bf(acc);
}

// ---------------------------------------------------------------------------
// Chunked scan over recomputed (alpha, xin) from bf16 fg/ig/xc.
// alpha = exp(-8*softplus(fb)*sig(fg)); xin = sqrt(1-a^2+1e-6)*sig(ig)*xc
// ---------------------------------------------------------------------------
#define CS_ 64
#define NC_ (T_ / CS_)

__device__ __forceinline__ void alpha_xin(const u16 fg, const u16 ig, const u16 xc,
                                          float sp, float& a, float& xin)
{
    a = expf(-8.0f * sp * sigmoidf_(bf2f(fg)));
    xin = sqrtf(1.f - a * a + 1e-6f) * sigmoidf_(bf2f(ig)) * bf2f(xc);
}

__global__ void scan1_kernel(const u16* __restrict__ fg, const u16* __restrict__ ig,
                             const u16* __restrict__ xc, const float* __restrict__ fb,
                             float* __restrict__ P, float* __restrict__ L)
{
    long idx = (long)blockIdx.x * blockDim.x + threadIdx.x;
    if (idx >= (long)B_ * NC_ * HH_) return;
    int ch = (int)(idx % HH_);
    int chunk = (int)((idx / HH_) % NC_);
    int b = (int)(idx / ((long)HH_ * NC_));
    long base = ((long)b * T_ + chunk * CS_) * HH_ + ch;
    float f = fb[ch];
    float sp = (f > 20.f) ? f : log1pf(expf(f));
    float p = 1.f, lacc = 0.f;
    for (int i = 0; i < CS_; i++) {
        long o = base + (long)i * HH_;
        float a, xin;
        alpha_xin(fg[o], ig[o], xc[o], sp, a, xin);
        lacc = a * lacc + xin;
        p *= a;
    }
    P[idx] = p; L[idx] = lacc;
}
__global__ void scan2_kernel(const float* __restrict__ P, const float* __restrict__ L,
                             float* __restrict__ I)
{
    long idx = (long)blockIdx.x * blockDim.x + threadIdx.x;
    if (idx >= (long)B_ * HH_) return;
    int ch = (int)(idx % HH_);
    int b = (int)(idx / HH_);
    float init = 0.f;
    for (int c = 0; c < NC_; c++) {
        long o = ((long)b * NC_ + c) * HH_ + ch;
        I[o] = init;
        init = P[o] * init + L[o];
    }
}
__global__ void scan3_kernel(const u16* __restrict__ fg, const u16* __restrict__ ig,
                             const u16* __restrict__ xc, const float* __restrict__ fb,
                             const float* __restrict__ I, const u16* __restrict__ gate,
                             u16* __restrict__ glu)
{
    long idx = (long)blockIdx.x * blockDim.x + threadIdx.x;
    if (idx >= (long)B_ * NC_ * HH_) return;
    int ch = (int)(idx % HH_);
    int chunk = (int)((idx / HH_) % NC_);
    int b = (int)(idx / ((long)HH_ * NC_));
    long base = ((long)b * T_ + chunk * CS_) * HH_ + ch;
    float f = fb[ch];
    float sp = (f > 20.f) ? f : log1pf(expf(f));
    float h = I[idx];
    for (int i = 0; i < CS_; i++) {
        long o = base + (long)i * HH_;
        float a, xin;
        alpha_xin(fg[o], ig[o], xc[o], sp, a, xin);
        h = a * h + xin;
        glu[o] = f2bf(gelu_exact(bf2f(gate[o])) * h);
    }
}

// ---------------------------------------------------------------------------
// launch
// ---------------------------------------------------------------------------
static inline long cdivl(long a, long b) { return (a + b - 1) / b; }

extern "C" void kernel_launch(void* const* d_in, const int* in_sizes, int n_in,
                              void* d_out, int out_size, void* d_ws, size_t ws_size,
                              hipStream_t stream)
{
    const float* x_in   = (const float*)d_in[0];
    const float* sn_g   = (const float*)d_in[1];
    const float* q_w    = (const float*)d_in[2];
    const float* kv_w   = (const float*)d_in[3];
    const float* ao_w   = (const float*)d_in[4];
    const float* sgn_g  = (const float*)d_in[5];
    const float* sg_grow   = (const float*)d_in[6];
    const float* sg_shrink = (const float*)d_in[7];
    const float* hn_g   = (const float*)d_in[8];
    const float* h_in_w = (const float*)d_in[9];
    const float* h_conv_w = (const float*)d_in[10];
    const float* h_conv_b = (const float*)d_in[11];
    const float* h_gates_w = (const float*)d_in[12];
    const float* h_gates_b = (const float*)d_in[13];
    const float* h_forget  = (const float*)d_in[14];
    const float* h_out_w   = (const float*)d_in[15];
    const float* hgn_g  = (const float*)d_in[16];
    const float* hg_grow   = (const float*)d_in[17];
    const float* hg_shrink = (const float*)d_in[18];
    float* out = (float*)d_out;

    // ---- workspace layout ----
    char* wsb = (char*)d_ws;
    u16* Wq  = (u16*)wsb;                 // 1,048,576
    u16* Wkv = Wq  + 1048576;             // 262,144
    u16* Wao = Wkv + 262144;              // 1,048,576
    u16* Wsg = Wao + 1048576;             // 4,194,304
    u16* Wss = Wsg + 4194304;             // 2,097,152
    u16* Whi = Wss + 2097152;             // 3,145,728
    u16* Whg = Whi + 3145728;             // 4,718,592
    u16* Who = Whg + 4718592;             // 1,572,864
    u16* Wgg = Who + 1572864;             // 4,194,304
    u16* Wgs = Wgg + 4194304;             // 2,097,152
    char* ab = wsb + 48758784;            // activation arena
    u16*   XN   = (u16*)(ab + 0);                    // [8192,1024] bf16
    char*  S2   = ab + 16777216;                     // 33.5 MB slot
    char*  S3   = ab + 50331648;                     // 25.2 MB slot
    char*  S4   = ab + 75497472;                     // 25.2 MB slot
    char*  S5   = ab + 100663296;                    // 25.2 MB slot
    char*  S6   = ab + 125829120;                    // 25.2 MB slot
    float* PB   = (float*)(ab + 150994944);
    float* LB   = (float*)(ab + 151781376);
    float* IB   = (float*)(ab + 152567808);

    const long M = (long)B_ * T_;   // 8192
    dim3 blk(256);
    const float* NULF = nullptr;
    const u16*   NULB = nullptr;

    // ---- weight conversion ----
    {
        const float* srcs[10] = {q_w, kv_w, ao_w, sg_grow, sg_shrink,
                                 h_in_w, h_gates_w, h_out_w, hg_grow, hg_shrink};
        u16* dsts[10] = {Wq, Wkv, Wao, Wsg, Wss, Whi, Whg, Who, Wgg, Wgs};
        long ns[10] = {1048576, 262144, 1048576, 4194304, 2097152,
                       3145728, 4718592, 1572864, 4194304, 2097152};
        for (int i = 0; i < 10; i++)
            cvt_kernel<<<dim3(cdivl(ns[i] / 8, 256)), blk, 0, stream>>>(srcs[i], dsts[i], ns[i]);
    }

    // ---- attention sublayer ----
    {
        float* Q  = (float*)S2;           // [8192,1024] f32
        float* KV = (float*)S3;           // [8192,256]  f32
        u16*   AT = (u16*)S4;             // [8192,1024] bf16
        rmsnorm_kernel<<<dim3(M), blk, 0, stream>>>(x_in, sn_g, XN);
        gemm_bf16_kernel<0,false><<<dim3(8, 64), blk, 0, stream>>>(XN, Wq, NULF, NULF, NULB, Q, M, 1024, 1024);
        gemm_bf16_kernel<0,false><<<dim3(2, 64), blk, 0, stream>>>(XN, Wkv, NULF, NULF, NULB, KV, M, 256, 1024);
        rope_kernel<<<dim3(cdivl((long)B_ * T_ * (HQ_ + 1) * 64, 256)), blk, 0, stream>>>(Q, KV);
        attn_mfma_kernel<<<dim3(T_ / 64, HQ_, B_), blk, 0, stream>>>(Q, KV, AT);
        gemm_bf16_kernel<2,false><<<dim3(8, 64), blk, 0, stream>>>(AT, Wao, NULF, x_in, NULB, out, M, 1024, 1024);
    }

    // ---- MLP 1 ----
    {
        u16* GATE = (u16*)S2;             // [8192,2048] bf16
        rmsnorm_kernel<<<dim3(M), blk, 0, stream>>>(out, sgn_g, XN);
        gemm_bf16_kernel<0,true><<<dim3(16, 64), blk, 0, stream>>>(XN, Wsg, NULF, NULF, NULB, GATE, M, 2048, 1024);
        gemm_bf16_kernel<3,true><<<dim3(16, 64), blk, 0, stream>>>(XN, Wsg + (size_t)2048 * 1024, NULF, NULF, GATE, GATE, M, 2048, 1024);
        gemm_bf16_kernel<2,false><<<dim3(8, 64), blk, 0, stream>>>(GATE, Wss, NULF, out, NULB, out, M, 1024, 2048);
    }

    // ---- hawk ----
    {
        u16* GATEH = (u16*)S2;            // [8192,1536] bf16
        u16* U     = (u16*)S3;            // [8192,1536] bf16 (reused as GLUH)
        u16* XC    = (u16*)S4;            // [8192,1536] bf16
        u16* FG    = (u16*)S5;            // [8192,1536] bf16
        u16* IG    = (u16*)S6;            // [8192,1536] bf16
        rmsnorm_kernel<<<dim3(M), blk, 0, stream>>>(out, hn_g, XN);
        gemm_bf16_kernel<0,true><<<dim3(12, 64), blk, 0, stream>>>(XN, Whi, NULF, NULF, NULB, GATEH, M, 1536, 1024);
        gemm_bf16_kernel<0,true><<<dim3(12, 64), blk, 0, stream>>>(XN, Whi + (size_t)1536 * 1024, NULF, NULF, NULB, U, M, 1536, 1024);
        conv_kernel<<<dim3(cdivl(M * HH_, 256)), blk, 0, stream>>>(U, h_conv_w, h_conv_b, XC);
        gemm_bf16_kernel<1,true><<<dim3(12, 64), blk, 0, stream>>>(XC, Whg, h_gates_b, NULF, NULB, FG, M, 1536, 1536);
        gemm_bf16_kernel<1,true><<<dim3(12, 64), blk, 0, stream>>>(XC, Whg + (size_t)1536 * 1536, h_gates_b + 1536, NULF, NULB, IG, M, 1536, 1536);
        scan1_kernel<<<dim3(cdivl((long)B_ * NC_ * HH_, 256)), blk, 0, stream>>>(FG, IG, XC, h_forget, PB, LB);
        scan2_kernel<<<dim3(cdivl((long)B_ * HH_, 256)), blk, 0, stream>>>(PB, LB, IB);
        scan3_kernel<<<dim3(cdivl((long)B_ * NC_ * HH_, 256)), blk, 0, stream>>>(FG, IG, XC, h_forget, IB, GATEH, U);
        gemm_bf16_kernel<2,false><<<dim3(8, 64), blk, 0, stream>>>(U, Who, NULF, out, NULB, out, M, 1024, 1536);
    }

    // ---- MLP 2 ----
    {
        u16* GATE = (u16*)S2;             // [8192,2048] bf16
        rmsnorm_kernel<<<dim3(M), blk, 0, stream>>>(out, hgn_g, XN);
        gemm_bf16_kernel<0,true><<<dim3(16, 64), blk, 0, stream>>>(XN, Wgg, NULF, NULF, NULB, GATE, M, 2048, 1024);
        gemm_bf16_kernel<3,true><<<dim3(16, 64), blk, 0, stream>>>(XN, Wgg + (size_t)2048 * 1024, NULF, NULF, GATE, GATE, M, 2048, 1024);
        gemm_bf16_kernel<2,false><<<dim3(8, 64), blk, 0, stream>>>(GATE, Wgs, NULF, out, NULB, out, M, 1024, 2048);
    }
}

// Round 6
// 1213.390 us; speedup vs baseline: 2.2308x; 1.0381x over previous
//
#include <hip/hip_runtime.h>
#include <hip/hip_bf16.h>
#include <math.h>

#define B_  2
#define T_  4096
#define D_  1024
#define HD_ 128
#define HQ_ 8
#define W_  1024
#define HH_ 1536
#define HG_ 2048
#define KC_ 4

typedef float  f32x4  __attribute__((ext_vector_type(4)));
typedef float  f32x2  __attribute__((ext_vector_type(2)));
typedef __bf16 bf16x8 __attribute__((ext_vector_type(8)));
typedef unsigned short u16;
typedef unsigned short u16x2 __attribute__((ext_vector_type(2)));
typedef unsigned short u16x4 __attribute__((ext_vector_type(4)));
typedef unsigned short u16x8 __attribute__((ext_vector_type(8)));

__device__ __forceinline__ u16 f2bf(float f) {
    unsigned int u = __builtin_bit_cast(unsigned int, f);
    u += 0x7fffu + ((u >> 16) & 1u);           // RNE
    return (u16)(u >> 16);
}
__device__ __forceinline__ float bf2f(u16 v) {
    unsigned int u = ((unsigned int)v) << 16;
    return __builtin_bit_cast(float, u);
}
__device__ __forceinline__ float gelu_exact(float x) {
    return 0.5f * x * (1.0f + erff(x * 0.70710678118654752f));
}
__device__ __forceinline__ float sigmoidf_(float x) {
    return 1.0f / (1.0f + expf(-x));
}

#define GLOAD16(gp, lp) __builtin_amdgcn_global_load_lds( \
    (const __attribute__((address_space(1))) void*)(gp),  \
    (__attribute__((address_space(3))) void*)(lp), 16, 0, 0)

// ---------------------------------------------------------------------------
// f32 -> bf16 conversion (weights)
// ---------------------------------------------------------------------------
__global__ void cvt_kernel(const float* __restrict__ src, u16* __restrict__ dst, long n)
{
    long i = ((long)blockIdx.x * blockDim.x + threadIdx.x) * 8;
    if (i >= n) return;
    f32x4 a = *(const f32x4*)(src + i);
    f32x4 b = *(const f32x4*)(src + i + 4);
    u16x4 ua, ub;
    ua.x = f2bf(a.x); ua.y = f2bf(a.y); ua.z = f2bf(a.z); ua.w = f2bf(a.w);
    ub.x = f2bf(b.x); ub.y = f2bf(b.y); ub.z = f2bf(b.z); ub.w = f2bf(b.w);
    *(u16x4*)(dst + i) = ua;
    *(u16x4*)(dst + i + 4) = ub;
}

// ---------------------------------------------------------------------------
// bf16 GEMM (m97 structure): out[M][N] = A[M][K] @ B[N][K]^T, A/B bf16.
// EPI: 0 none | 1 +bias | 2 +res(f32) | 3 glu: out=gelu(gatebuf)*acc
// ---------------------------------------------------------------------------
template<int EPI, bool OBF>
__global__ __launch_bounds__(256)
void gemm_bf16_kernel(const u16* __restrict__ A, const u16* __restrict__ Bw,
                      const float* __restrict__ bias, const float* __restrict__ res,
                      const u16* gatebuf, void* outv,
                      int M, int N, int K)
{
    __shared__ u16 lA[128 * 64];
    __shared__ u16 lB[128 * 64];
    const int n0 = blockIdx.x * 128, m0 = blockIdx.y * 128;
    const int tid = threadIdx.x, w = tid >> 6, l = tid & 63;
    const int wr = w >> 1, wc = w & 1, lr = l & 15, lg = l >> 4;

    f32x4 acc[4][4];
#pragma unroll
    for (int i = 0; i < 4; i++)
#pragma unroll
        for (int j = 0; j < 4; j++) acc[i][j] = {0.f, 0.f, 0.f, 0.f};

    const int rl = l >> 3;
    const int cb = (l & 7) * 8;
    const u16* gA = A + (long)(m0 + w * 32 + rl) * K + cb;
    const u16* gB = Bw + (long)(n0 + w * 32 + rl) * K + cb;
    u16* lAw = &lA[w * 2048];
    u16* lBw = &lB[w * 2048];

    for (int kk = 0; kk < K; kk += 64) {
        __syncthreads();
#pragma unroll
        for (int c = 0; c < 4; c++) {
            GLOAD16(gA + (long)c * 8 * K + kk, lAw + c * 512);
            GLOAD16(gB + (long)c * 8 * K + kk, lBw + c * 512);
        }
        __syncthreads();
#pragma unroll
        for (int ks = 0; ks < 2; ks++) {
            bf16x8 af[4], bfr[4];
#pragma unroll
            for (int m = 0; m < 4; m++)
                af[m] = *(const bf16x8*)&lA[(wr * 64 + m * 16 + lr) * 64 + ks * 32 + lg * 8];
#pragma unroll
            for (int n = 0; n < 4; n++)
                bfr[n] = *(const bf16x8*)&lB[(wc * 64 + n * 16 + lr) * 64 + ks * 32 + lg * 8];
#pragma unroll
            for (int m = 0; m < 4; m++)
#pragma unroll
                for (int n = 0; n < 4; n++)
                    acc[m][n] = __builtin_amdgcn_mfma_f32_16x16x32_bf16(af[m], bfr[n], acc[m][n], 0, 0, 0);
        }
    }

#pragma unroll
    for (int m = 0; m < 4; m++)
#pragma unroll
        for (int n = 0; n < 4; n++) {
            const int col = n0 + wc * 64 + n * 16 + lr;
            const float bv = (EPI == 1) ? bias[col] : 0.f;
#pragma unroll
            for (int r = 0; r < 4; r++) {
                const int row = m0 + wr * 64 + m * 16 + lg * 4 + r;
                const long idx = (long)row * N + col;
                float v = acc[m][n][r] + bv;
                if (EPI == 2) v += res[idx];
                if (EPI == 3) v = gelu_exact(bf2f(gatebuf[idx])) * v;
                if (OBF) ((u16*)outv)[idx] = f2bf(v);
                else     ((float*)outv)[idx] = v;
            }
        }
}

// ---------------------------------------------------------------------------
// RMSNorm -> bf16
// ---------------------------------------------------------------------------
__global__ __launch_bounds__(256)
void rmsnorm_kernel(const float* __restrict__ x, const float* __restrict__ g,
                    u16* __restrict__ out)
{
    const long row = blockIdx.x;
    const int tid = threadIdx.x;
    const float* xp = x + row * D_;
    f32x4 v = *(const f32x4*)(xp + tid * 4);
    float ss = v.x * v.x + v.y * v.y + v.z * v.z + v.w * v.w;
#pragma unroll
    for (int o = 1; o < 64; o <<= 1) ss += __shfl_xor(ss, o);
    __shared__ float ps[4];
    if ((tid & 63) == 0) ps[tid >> 6] = ss;
    __syncthreads();
    float tot = ps[0] + ps[1] + ps[2] + ps[3];
    float inv = rsqrtf(tot) * 32.0f;     // sqrt(1024)=32
    f32x4 gv = *(const f32x4*)(g + tid * 4);
    u16x4 o4;
    o4.x = f2bf(gv.x * v.x * inv); o4.y = f2bf(gv.y * v.y * inv);
    o4.z = f2bf(gv.z * v.z * inv); o4.w = f2bf(gv.w * v.w * inv);
    *(u16x4*)(out + row * D_ + tid * 4) = o4;
}

// ---------------------------------------------------------------------------
// RoPE: read f32 Q and KV, write bf16 Qb [B,T,HQ,128] and Kb [B,T,128]
// ---------------------------------------------------------------------------
__global__ void rope_bf16_kernel(const float* __restrict__ q, const float* __restrict__ kv,
                                 u16* __restrict__ qb, u16* __restrict__ kb)
{
    const long NQ = (long)B_ * T_ * HQ_ * 64;
    const long NK = (long)B_ * T_ * 64;
    long idx = (long)blockIdx.x * blockDim.x + threadIdx.x;
    if (idx >= NQ + NK) return;
    int i; long t; const float* src; u16* dst;
    if (idx < NQ) {
        i = idx & 63;
        long bth = idx >> 6;
        t = (bth / HQ_) % T_;
        src = q + bth * HD_ + 2 * i;
        dst = qb + bth * HD_ + 2 * i;
    } else {
        long k = idx - NQ;
        i = k & 63;
        long bt = k >> 6;
        t = bt % T_;
        src = kv + bt * (2 * HD_) + 2 * i;
        dst = kb + bt * HD_ + 2 * i;
    }
    float freq = exp2f(-(float)i * 0.20762050593046014f);  // log2(1e4)/64
    float ang = (float)t * freq;
    float sn, cs;
    sincosf(ang, &sn, &cs);
    f32x2 xv = *(const f32x2*)src;
    u16x2 yv;
    yv.x = f2bf(xv.x * cs - xv.y * sn);
    yv.y = f2bf(xv.x * sn + xv.y * cs);
    *(u16x2*)dst = yv;
}

// ---------------------------------------------------------------------------
// V transpose: KV f32 [B,T,2,128] (v half) -> Vt bf16 [B,128,T]
// block: 64 t x 64 d tile
// ---------------------------------------------------------------------------
__global__ __launch_bounds__(256)
void vtrans_kernel(const float* __restrict__ kv, u16* __restrict__ vt)
{
    __shared__ float tile[64][65];
    const int t0 = blockIdx.x * 64, d0 = blockIdx.y * 64, b = blockIdx.z;
    const int tid = threadIdx.x;
    {
        const int tl = tid & 63, dg = tid >> 6;      // dg 0..3
        const float* vp = kv + (((long)b * T_ + t0 + tl) * 2 + 1) * HD_ + d0 + dg * 16;
#pragma unroll
        for (int j = 0; j < 4; j++) {
            f32x4 v = *(const f32x4*)(vp + j * 4);
            tile[dg * 16 + j * 4 + 0][tl] = v.x;
            tile[dg * 16 + j * 4 + 1][tl] = v.y;
            tile[dg * 16 + j * 4 + 2][tl] = v.z;
            tile[dg * 16 + j * 4 + 3][tl] = v.w;
        }
    }
    __syncthreads();
    {
        const int dl = tid >> 2, tg = (tid & 3) * 16;
        u16x8 a, c;
#pragma unroll
        for (int j = 0; j < 8; j++) a[j] = f2bf(tile[dl][tg + j]);
#pragma unroll
        for (int j = 0; j < 8; j++) c[j] = f2bf(tile[dl][tg + 8 + j]);
        u16* dst = vt + ((long)b * HD_ + d0 + dl) * T_ + t0 + tg;
        *(u16x8*)dst = a;
        *(u16x8*)(dst + 8) = c;
    }
}

// ---------------------------------------------------------------------------
// MFMA sliding-window attention v2: bf16 inputs, global_load_lds staging,
// XOR-swizzled LDS (slot ^= row&7 on both the staging source and the reads).
// Ksh [64 key][128 d] (256B rows, 16 slots), Vsh [128 d][64 key] (128B rows,
// 8 slots). Psh per-wave padded (PLD=72), normal ds_writes.
// ---------------------------------------------------------------------------
#define PLD 72

__global__ __launch_bounds__(256)
void attn_mfma2_kernel(const u16* __restrict__ qb, const u16* __restrict__ kb,
                       const u16* __restrict__ vt, u16* __restrict__ o)
{
    __shared__ u16 Ksh[64 * 128];
    __shared__ u16 Vsh[128 * 64];
    __shared__ u16 Psh[4 * 16 * PLD];

    const int qt = blockIdx.x, h = blockIdx.y, b = blockIdx.z;
    const int q0 = qt * 64;
    const int tid = threadIdx.x;
    const int w = tid >> 6, l = tid & 63;
    const int lr = l & 15, lg = l >> 4;

    // Q fragments straight from global bf16
    bf16x8 qfr[4];
    {
        const u16* qp = qb + (((long)b * T_ + q0 + w * 16 + lr) * HQ_ + h) * HD_;
#pragma unroll
        for (int kt = 0; kt < 4; kt++)
            qfr[kt] = *(const bf16x8*)(qp + kt * 32 + lg * 8);
    }

    // lane-constant pre-swizzled staging offsets (elements)
    int oK[4], oV[4];
#pragma unroll
    for (int i = 0; i < 4; i++) {
        int krow = w * 16 + i * 4 + (l >> 4);
        int kc8 = (l & 15) ^ (krow & 7);
        oK[i] = krow * 128 + kc8 * 8;
        int vrow = w * 32 + i * 8 + (l >> 3);
        int vc8 = (l & 7) ^ (vrow & 7);
        oV[i] = vrow * T_ + vc8 * 8;
    }
    const u16* kbase = kb + (long)b * T_ * HD_;
    const u16* vbase = vt + (long)b * HD_ * T_;

    f32x4 oacc[8];
#pragma unroll
    for (int dt = 0; dt < 8; dt++) oacc[dt] = {0.f, 0.f, 0.f, 0.f};
    float mrun[4], srun[4];
#pragma unroll
    for (int r = 0; r < 4; r++) { mrun[r] = -1e30f; srun[r] = 0.f; }

    const int kt_lo = (q0 >= W_) ? (q0 - W_) : 0;
    const int sw = lr & 7;   // read-side row swizzle (row&7 == lr&7 for all our rows)

    for (int kt0 = kt_lo; kt0 <= q0; kt0 += 64) {
        __syncthreads();
#pragma unroll
        for (int i = 0; i < 4; i++) {
            GLOAD16(kbase + (long)kt0 * HD_ + oK[i], &Ksh[w * 2048 + i * 512]);
            GLOAD16(vbase + kt0 + oV[i], &Vsh[w * 2048 + i * 512]);
        }
        __syncthreads();

        // QK^T (swizzled K reads)
        f32x4 s[4];
#pragma unroll
        for (int ct = 0; ct < 4; ct++) {
            s[ct] = {0.f, 0.f, 0.f, 0.f};
#pragma unroll
            for (int kt = 0; kt < 4; kt++) {
                bf16x8 kf = *(const bf16x8*)&Ksh[(ct * 16 + lr) * 128 + (((kt * 4 + lg) ^ sw) * 8)];
                s[ct] = __builtin_amdgcn_mfma_f32_16x16x32_bf16(qfr[kt], kf, s[ct], 0, 0, 0);
            }
        }

        // scale + mask + tile max
        float tmax[4] = {-3e38f, -3e38f, -3e38f, -3e38f};
#pragma unroll
        for (int ct = 0; ct < 4; ct++) {
            const int kpos = kt0 + ct * 16 + lr;
#pragma unroll
            for (int r = 0; r < 4; r++) {
                const int qpos = q0 + w * 16 + lg * 4 + r;
                float v = s[ct][r] * 0.08838834764831845f;
                bool valid = (kpos <= qpos) && (kpos + W_ >= qpos);
                v = valid ? v : -3e38f;
                s[ct][r] = v;
                tmax[r] = fmaxf(tmax[r], v);
            }
        }
#pragma unroll
        for (int r = 0; r < 4; r++)
#pragma unroll
            for (int msk = 1; msk < 16; msk <<= 1)
                tmax[r] = fmaxf(tmax[r], __shfl_xor(tmax[r], msk));

        float fr[4], psum[4];
#pragma unroll
        for (int r = 0; r < 4; r++) {
            float mnew = fmaxf(mrun[r], tmax[r]);
            fr[r] = __expf(mrun[r] - mnew);
            mrun[r] = mnew;
            srun[r] *= fr[r];
            psum[r] = 0.f;
        }
#pragma unroll
        for (int dt = 0; dt < 8; dt++) {
            oacc[dt][0] *= fr[0]; oacc[dt][1] *= fr[1];
            oacc[dt][2] *= fr[2]; oacc[dt][3] *= fr[3];
        }

        u16* pw = &Psh[w * 16 * PLD];
#pragma unroll
        for (int ct = 0; ct < 4; ct++)
#pragma unroll
            for (int r = 0; r < 4; r++) {
                float p = __expf(s[ct][r] - mrun[r]);
                psum[r] += p;
                pw[(lg * 4 + r) * PLD + ct * 16 + lr] = f2bf(p);
            }
#pragma unroll
        for (int r = 0; r < 4; r++) {
#pragma unroll
            for (int msk = 1; msk < 16; msk <<= 1)
                psum[r] += __shfl_xor(psum[r], msk);
            srun[r] += psum[r];
        }

        asm volatile("s_waitcnt lgkmcnt(0)" ::: "memory");
        bf16x8 pa0 = *(const bf16x8*)&pw[lr * PLD + lg * 8];
        bf16x8 pa1 = *(const bf16x8*)&pw[lr * PLD + 32 + lg * 8];
#pragma unroll
        for (int dt = 0; dt < 8; dt++) {
            bf16x8 vf0 = *(const bf16x8*)&Vsh[(dt * 16 + lr) * 64 + ((lg ^ sw) * 8)];
            bf16x8 vf1 = *(const bf16x8*)&Vsh[(dt * 16 + lr) * 64 + (((4 + lg) ^ sw) * 8)];
            oacc[dt] = __builtin_amdgcn_mfma_f32_16x16x32_bf16(pa0, vf0, oacc[dt], 0, 0, 0);
            oacc[dt] = __builtin_amdgcn_mfma_f32_16x16x32_bf16(pa1, vf1, oacc[dt], 0, 0, 0);
        }
    }

#pragma unroll
    for (int r = 0; r < 4; r++) {
        const int qpos = q0 + w * 16 + lg * 4 + r;
        float inv = 1.f / srun[r];
        u16* op = o + ((long)b * T_ + qpos) * (HQ_ * HD_) + h * HD_;
#pragma unroll
        for (int dt = 0; dt < 8; dt++)
            op[dt * 16 + lr] = f2bf(oacc[dt][r] * inv);
    }
}

// ---------------------------------------------------------------------------
// Depthwise causal conv K=4 over bf16 u [8192,1536] -> bf16 xc
// ---------------------------------------------------------------------------
__global__ void conv_kernel(const u16* __restrict__ u, const float* __restrict__ w,
                            const float* __restrict__ bias, u16* __restrict__ xc)
{
    long idx = (long)blockIdx.x * blockDim.x + threadIdx.x;
    if (idx >= (long)B_ * T_ * HH_) return;
    int ch = (int)(idx % HH_);
    long row = idx / HH_;
    int t = (int)(row % T_);
    float acc = bias[ch];
#pragma unroll
    for (int k = 0; k < KC_; k++) {
        int ts = t - 3 + k;
        if (ts >= 0) acc += bf2f(u[(row - t + ts) * HH_ + ch]) * w[ch * KC_ + k];
    }
    xc[idx] = f2bf(acc);
}

// ---------------------------------------------------------------------------
// Chunked scan over recomputed (alpha, xin) from bf16 fg/ig/xc.
// ---------------------------------------------------------------------------
#define CS_ 64
#define NC_ (T_ / CS_)

__device__ __forceinline__ void alpha_xin(const u16 fg, const u16 ig, const u16 xc,
                                          float sp, float& a, float& xin)
{
    a = expf(-8.0f * sp * sigmoidf_(bf2f(fg)));
    xin = sqrtf(1.f - a * a + 1e-6f) * sigmoidf_(bf2f(ig)) * bf2f(xc);
}

__global__ void scan1_kernel(const u16* __restrict__ fg, const u16* __restrict__ ig,
                             const u16* __restrict__ xc, const float* __restrict__ fb,
                             float* __restrict__ P, float* __restrict__ L)
{
    long idx = (long)blockIdx.x * blockDim.x + threadIdx.x;
    if (idx >= (long)B_ * NC_ * HH_) return;
    int ch = (int)(idx % HH_);
    int chunk = (int)((idx / HH_) % NC_);
    int b = (int)(idx / ((long)HH_ * NC_));
    long base = ((long)b * T_ + chunk * CS_) * HH_ + ch;
    float f = fb[ch];
    float sp = (f > 20.f) ? f : log1pf(expf(f));
    float p = 1.f, lacc = 0.f;
    for (int i = 0; i < CS_; i++) {
        long o = base + (long)i * HH_;
        float a, xin;
        alpha_xin(fg[o], ig[o], xc[o], sp, a, xin);
        lacc = a * lacc + xin;
        p *= a;
    }
    P[idx] = p; L[idx] = lacc;
}
__global__ void scan2_kernel(const float* __restrict__ P, const float* __restrict__ L,
                             float* __restrict__ I)
{
    long idx = (long)blockIdx.x * blockDim.x + threadIdx.x;
    if (idx >= (long)B_ * HH_) return;
    int ch = (int)(idx % HH_);
    int b = (int)(idx / HH_);
    float init = 0.f;
    for (int c = 0; c < NC_; c++) {
        long o = ((long)b * NC_ + c) * HH_ + ch;
        I[o] = init;
        init = P[o] * init + L[o];
    }
}
__global__ void scan3_kernel(const u16* __restrict__ fg, const u16* __restrict__ ig,
                             const u16* __restrict__ xc, const float* __restrict__ fb,
                             const float* __restrict__ I, const u16* __restrict__ gate,
                             u16* __restrict__ glu)
{
    long idx = (long)blockIdx.x * blockDim.x + threadIdx.x;
    if (idx >= (long)B_ * NC_ * HH_) return;
    int ch = (int)(idx % HH_);
    int chunk = (int)((idx / HH_) % NC_);
    int b = (int)(idx / ((long)HH_ * NC_));
    long base = ((long)b * T_ + chunk * CS_) * HH_ + ch;
    float f = fb[ch];
    float sp = (f > 20.f) ? f : log1pf(expf(f));
    float h = I[idx];
    for (int i = 0; i < CS_; i++) {
        long o = base + (long)i * HH_;
        float a, xin;
        alpha_xin(fg[o], ig[o], xc[o], sp, a, xin);
        h = a * h + xin;
        glu[o] = f2bf(gelu_exact(bf2f(gate[o])) * h);
    }
}

// ---------------------------------------------------------------------------
// launch
// ---------------------------------------------------------------------------
static inline long cdivl(long a, long b) { return (a + b - 1) / b; }

extern "C" void kernel_launch(void* const* d_in, const int* in_sizes, int n_in,
                              void* d_out, int out_size, void* d_ws, size_t ws_size,
                              hipStream_t stream)
{
    const float* x_in   = (const float*)d_in[0];
    const float* sn_g   = (const float*)d_in[1];
    const float* q_w    = (const float*)d_in[2];
    const float* kv_w   = (const float*)d_in[3];
    const float* ao_w   = (const float*)d_in[4];
    const float* sgn_g  = (const float*)d_in[5];
    const float* sg_grow   = (const float*)d_in[6];
    const float* sg_shrink = (const float*)d_in[7];
    const float* hn_g   = (const float*)d_in[8];
    const float* h_in_w = (const float*)d_in[9];
    const float* h_conv_w = (const float*)d_in[10];
    const float* h_conv_b = (const float*)d_in[11];
    const float* h_gates_w = (const float*)d_in[12];
    const float* h_gates_b = (const float*)d_in[13];
    const float* h_forget  = (const float*)d_in[14];
    const float* h_out_w   = (const float*)d_in[15];
    const float* hgn_g  = (const float*)d_in[16];
    const float* hg_grow   = (const float*)d_in[17];
    const float* hg_shrink = (const float*)d_in[18];
    float* out = (float*)d_out;

    // ---- workspace layout ----
    char* wsb = (char*)d_ws;
    u16* Wq  = (u16*)wsb;                 // 1,048,576
    u16* Wkv = Wq  + 1048576;             // 262,144
    u16* Wao = Wkv + 262144;              // 1,048,576
    u16* Wsg = Wao + 1048576;             // 4,194,304
    u16* Wss = Wsg + 4194304;             // 2,097,152
    u16* Whi = Wss + 2097152;             // 3,145,728
    u16* Whg = Whi + 3145728;             // 4,718,592
    u16* Who = Whg + 4718592;             // 1,572,864
    u16* Wgg = Who + 1572864;             // 4,194,304
    u16* Wgs = Wgg + 4194304;             // 2,097,152
    char* ab = wsb + 48758784;            // activation arena
    u16*   XN   = (u16*)(ab + 0);                    // [8192,1024] bf16
    char*  S2   = ab + 16777216;                     // 33.5 MB slot
    char*  S3   = ab + 50331648;                     // 25.2 MB slot
    char*  S4   = ab + 75497472;                     // 25.2 MB slot
    char*  S5   = ab + 100663296;                    // 25.2 MB slot
    char*  S6   = ab + 125829120;                    // 25.2 MB slot
    float* PB   = (float*)(ab + 150994944);
    float* LB   = (float*)(ab + 151781376);
    float* IB   = (float*)(ab + 152567808);

    const long M = (long)B_ * T_;   // 8192
    dim3 blk(256);
    const float* NULF = nullptr;
    const u16*   NULB = nullptr;

    // ---- weight conversion ----
    {
        const float* srcs[10] = {q_w, kv_w, ao_w, sg_grow, sg_shrink,
                                 h_in_w, h_gates_w, h_out_w, hg_grow, hg_shrink};
        u16* dsts[10] = {Wq, Wkv, Wao, Wsg, Wss, Whi, Whg, Who, Wgg, Wgs};
        long ns[10] = {1048576, 262144, 1048576, 4194304, 2097152,
                       3145728, 4718592, 1572864, 4194304, 2097152};
        for (int i = 0; i < 10; i++)
            cvt_kernel<<<dim3(cdivl(ns[i] / 8, 256)), blk, 0, stream>>>(srcs[i], dsts[i], ns[i]);
    }

    // ---- attention sublayer ----
    {
        float* Q  = (float*)S2;                      // [8192,1024] f32
        float* KV = (float*)S3;                      // [8192,256]  f32
        u16*   Kb = (u16*)(S3 + 8388608);            // [B,T,128] bf16
        u16*   Vt = (u16*)(S3 + 10485760);           // [B,128,T] bf16
        u16*   Qb = (u16*)S4;                        // [B,T,HQ,128] bf16
        u16*   AT = (u16*)S5;                        // [8192,1024] bf16
        rmsnorm_kernel<<<dim3(M), blk, 0, stream>>>(x_in, sn_g, XN);
        gemm_bf16_kernel<0,false><<<dim3(8, 64), blk, 0, stream>>>(XN, Wq, NULF, NULF, NULB, Q, M, 1024, 1024);
        gemm_bf16_kernel<0,false><<<dim3(2, 64), blk, 0, stream>>>(XN, Wkv, NULF, NULF, NULB, KV, M, 256, 1024);
        rope_bf16_kernel<<<dim3(cdivl((long)B_ * T_ * (HQ_ + 1) * 64, 256)), blk, 0, stream>>>(Q, KV, Qb, Kb);
        vtrans_kernel<<<dim3(T_ / 64, 2, B_), blk, 0, stream>>>(KV, Vt);
        attn_mfma2_kernel<<<dim3(T_ / 64, HQ_, B_), blk, 0, stream>>>(Qb, Kb, Vt, AT);
        gemm_bf16_kernel<2,false><<<dim3(8, 64), blk, 0, stream>>>(AT, Wao, NULF, x_in, NULB, out, M, 1024, 1024);
    }

    // ---- MLP 1 ----
    {
        u16* GATE = (u16*)S2;             // [8192,2048] bf16
        rmsnorm_kernel<<<dim3(M), blk, 0, stream>>>(out, sgn_g, XN);
        gemm_bf16_kernel<0,true><<<dim3(16, 64), blk, 0, stream>>>(XN, Wsg, NULF, NULF, NULB, GATE, M, 2048, 1024);
        gemm_bf16_kernel<3,true><<<dim3(16, 64), blk, 0, stream>>>(XN, Wsg + (size_t)2048 * 1024, NULF, NULF, GATE, GATE, M, 2048, 1024);
        gemm_bf16_kernel<2,false><<<dim3(8, 64), blk, 0, stream>>>(GATE, Wss, NULF, out, NULB, out, M, 1024, 2048);
    }

    // ---- hawk ----
    {
        u16* GATEH = (u16*)S2;            // [8192,1536] bf16
        u16* U     = (u16*)S3;            // [8192,1536] bf16 (reused as GLUH)
        u16* XC    = (u16*)S4;            // [8192,1536] bf16
        u16* FG    = (u16*)S5;            // [8192,1536] bf16
        u16* IG    = (u16*)S6;            // [8192,1536] bf16
        rmsnorm_kernel<<<dim3(M), blk, 0, stream>>>(out, hn_g, XN);
        gemm_bf16_kernel<0,true><<<dim3(12, 64), blk, 0, stream>>>(XN, Whi, NULF, NULF, NULB, GATEH, M, 1536, 1024);
        gemm_bf16_kernel<0,true><<<dim3(12, 64), blk, 0, stream>>>(XN, Whi + (size_t)1536 * 1024, NULF, NULF, NULB, U, M, 1536, 1024);
        conv_kernel<<<dim3(cdivl(M * HH_, 256)), blk, 0, stream>>>(U, h_conv_w, h_conv_b, XC);
        gemm_bf16_kernel<1,true><<<dim3(12, 64), blk, 0, stream>>>(XC, Whg, h_gates_b, NULF, NULB, FG, M, 1536, 1536);
        gemm_bf16_kernel<1,true><<<dim3(12, 64), blk, 0, stream>>>(XC, Whg + (size_t)1536 * 1536, h_gates_b + 1536, NULF, NULB, IG, M, 1536, 1536);
        scan1_kernel<<<dim3(cdivl((long)B_ * NC_ * HH_, 256)), blk, 0, stream>>>(FG, IG, XC, h_forget, PB, LB);
        scan2_kernel<<<dim3(cdivl((long)B_ * HH_, 256)), blk, 0, stream>>>(PB, LB, IB);
        scan3_kernel<<<dim3(cdivl((long)B_ * NC_ * HH_, 256)), blk, 0, stream>>>(FG, IG, XC, h_forget, IB, GATEH, U);
        gemm_bf16_kernel<2,false><<<dim3(8, 64), blk, 0, stream>>>(U, Who, NULF, out, NULB, out, M, 1024, 1536);
    }

    // ---- MLP 2 ----
    {
        u16* GATE = (u16*)S2;             // [8192,2048] bf16
        rmsnorm_kernel<<<dim3(M), blk, 0, stream>>>(out, hgn_g, XN);
        gemm_bf16_kernel<0,true><<<dim3(16, 64), blk, 0, stream>>>(XN, Wgg, NULF, NULF, NULB, GATE, M, 2048, 1024);
        gemm_bf16_kernel<3,true><<<dim3(16, 64), blk, 0, stream>>>(XN, Wgg + (size_t)2048 * 1024, NULF, NULF, GATE, GATE, M, 2048, 1024);
        gemm_bf16_kernel<2,false><<<dim3(8, 64), blk, 0, stream>>>(GATE, Wgs, NULF, out, NULB, out, M, 1024, 2048);
    }
}

// Round 7
// 1106.005 us; speedup vs baseline: 2.4474x; 1.0971x over previous
//
#include <hip/hip_runtime.h>
#include <hip/hip_bf16.h>
#include <math.h>

#define B_  2
#define T_  4096
#define D_  1024
#define HD_ 128
#define HQ_ 8
#define W_  1024
#define HH_ 1536
#define HG_ 2048
#define KC_ 4

typedef float  f32x4  __attribute__((ext_vector_type(4)));
typedef float  f32x2  __attribute__((ext_vector_type(2)));
typedef __bf16 bf16x8 __attribute__((ext_vector_type(8)));
typedef unsigned short u16;
typedef unsigned short u16x2 __attribute__((ext_vector_type(2)));
typedef unsigned short u16x4 __attribute__((ext_vector_type(4)));
typedef unsigned short u16x8 __attribute__((ext_vector_type(8)));

__device__ __forceinline__ u16 f2bf(float f) {
    unsigned int u = __builtin_bit_cast(unsigned int, f);
    u += 0x7fffu + ((u >> 16) & 1u);           // RNE
    return (u16)(u >> 16);
}
__device__ __forceinline__ float bf2f(u16 v) {
    unsigned int u = ((unsigned int)v) << 16;
    return __builtin_bit_cast(float, u);
}
__device__ __forceinline__ float gelu_exact(float x) {
    return 0.5f * x * (1.0f + erff(x * 0.70710678118654752f));
}
__device__ __forceinline__ float sigmoidf_(float x) {
    return 1.0f / (1.0f + expf(-x));
}

#define GLOAD16(gp, lp) __builtin_amdgcn_global_load_lds( \
    (const __attribute__((address_space(1))) void*)(gp),  \
    (__attribute__((address_space(3))) void*)(lp), 16, 0, 0)

// ---------------------------------------------------------------------------
// f32 -> bf16 conversion (weights)
// ---------------------------------------------------------------------------
__global__ void cvt_kernel(const float* __restrict__ src, u16* __restrict__ dst, long n)
{
    long i = ((long)blockIdx.x * blockDim.x + threadIdx.x) * 8;
    if (i >= n) return;
    f32x4 a = *(const f32x4*)(src + i);
    f32x4 b = *(const f32x4*)(src + i + 4);
    u16x4 ua, ub;
    ua.x = f2bf(a.x); ua.y = f2bf(a.y); ua.z = f2bf(a.z); ua.w = f2bf(a.w);
    ub.x = f2bf(b.x); ub.y = f2bf(b.y); ub.z = f2bf(b.z); ub.w = f2bf(b.w);
    *(u16x4*)(dst + i) = ua;
    *(u16x4*)(dst + i + 4) = ub;
}

// ---------------------------------------------------------------------------
// bf16 GEMM (m97 structure + T2 XOR swizzle): out = A[M][K] @ B[N][K]^T.
// 128x128 tile, BK=64, global_load_lds(16B) into LINEAR LDS; the 16B slot
// within each 64-elem row is XOR-swizzled by (row&7) on BOTH the global
// source address (staging) and the ds_read (rule #21 involution), killing
// the 16-way bank conflict of the 128B row stride.
// EPI: 0 none | 1 +bias | 2 +res(f32) | 3 glu: out=gelu(gatebuf)*acc
// ---------------------------------------------------------------------------
template<int EPI, bool OBF>
__global__ __launch_bounds__(256)
void gemm_bf16_kernel(const u16* __restrict__ A, const u16* __restrict__ Bw,
                      const float* __restrict__ bias, const float* __restrict__ res,
                      const u16* gatebuf, void* outv,
                      int M, int N, int K)
{
    __shared__ u16 lA[128 * 64];
    __shared__ u16 lB[128 * 64];
    const int n0 = blockIdx.x * 128, m0 = blockIdx.y * 128;
    const int tid = threadIdx.x, w = tid >> 6, l = tid & 63;
    const int wr = w >> 1, wc = w & 1, lr = l & 15, lg = l >> 4;

    f32x4 acc[4][4];
#pragma unroll
    for (int i = 0; i < 4; i++)
#pragma unroll
        for (int j = 0; j < 4; j++) acc[i][j] = {0.f, 0.f, 0.f, 0.f};

    // staging: lane l -> LDS row (w*32 + c*8 + (l>>3)), slot (l&7).
    // row&7 == l>>3 for every chunk c, so the inverse-swizzled source
    // column ((l&7)^(l>>3))*8 is a lane constant.
    const int rl = l >> 3;
    const int cbs = ((l & 7) ^ rl) * 8;
    const u16* gA = A + (long)(m0 + w * 32 + rl) * K + cbs;
    const u16* gB = Bw + (long)(n0 + w * 32 + rl) * K + cbs;
    u16* lAw = &lA[w * 2048];
    u16* lBw = &lB[w * 2048];

    for (int kk = 0; kk < K; kk += 64) {
        __syncthreads();
#pragma unroll
        for (int c = 0; c < 4; c++) {
            GLOAD16(gA + (long)c * 8 * K + kk, lAw + c * 512);
            GLOAD16(gB + (long)c * 8 * K + kk, lBw + c * 512);
        }
        __syncthreads();
        const int swz = lr & 7;          // == row&7 for all fragment rows
#pragma unroll
        for (int ks = 0; ks < 2; ks++) {
            bf16x8 af[4], bfr[4];
#pragma unroll
            for (int m = 0; m < 4; m++)
                af[m] = *(const bf16x8*)&lA[(wr * 64 + m * 16 + lr) * 64 + (((ks * 4 + lg) ^ swz) * 8)];
#pragma unroll
            for (int n = 0; n < 4; n++)
                bfr[n] = *(const bf16x8*)&lB[(wc * 64 + n * 16 + lr) * 64 + (((ks * 4 + lg) ^ swz) * 8)];
#pragma unroll
            for (int m = 0; m < 4; m++)
#pragma unroll
                for (int n = 0; n < 4; n++)
                    acc[m][n] = __builtin_amdgcn_mfma_f32_16x16x32_bf16(af[m], bfr[n], acc[m][n], 0, 0, 0);
        }
    }

#pragma unroll
    for (int m = 0; m < 4; m++)
#pragma unroll
        for (int n = 0; n < 4; n++) {
            const int col = n0 + wc * 64 + n * 16 + lr;
            const float bv = (EPI == 1) ? bias[col] : 0.f;
#pragma unroll
            for (int r = 0; r < 4; r++) {
                const int row = m0 + wr * 64 + m * 16 + lg * 4 + r;
                const long idx = (long)row * N + col;
                float v = acc[m][n][r] + bv;
                if (EPI == 2) v += res[idx];
                if (EPI == 3) v = gelu_exact(bf2f(gatebuf[idx])) * v;
                if (OBF) ((u16*)outv)[idx] = f2bf(v);
                else     ((float*)outv)[idx] = v;
            }
        }
}

// ---------------------------------------------------------------------------
// RMSNorm -> bf16
// ---------------------------------------------------------------------------
__global__ __launch_bounds__(256)
void rmsnorm_kernel(const float* __restrict__ x, const float* __restrict__ g,
                    u16* __restrict__ out)
{
    const long row = blockIdx.x;
    const int tid = threadIdx.x;
    const float* xp = x + row * D_;
    f32x4 v = *(const f32x4*)(xp + tid * 4);
    float ss = v.x * v.x + v.y * v.y + v.z * v.z + v.w * v.w;
#pragma unroll
    for (int o = 1; o < 64; o <<= 1) ss += __shfl_xor(ss, o);
    __shared__ float ps[4];
    if ((tid & 63) == 0) ps[tid >> 6] = ss;
    __syncthreads();
    float tot = ps[0] + ps[1] + ps[2] + ps[3];
    float inv = rsqrtf(tot) * 32.0f;     // sqrt(1024)=32
    f32x4 gv = *(const f32x4*)(g + tid * 4);
    u16x4 o4;
    o4.x = f2bf(gv.x * v.x * inv); o4.y = f2bf(gv.y * v.y * inv);
    o4.z = f2bf(gv.z * v.z * inv); o4.w = f2bf(gv.w * v.w * inv);
    *(u16x4*)(out + row * D_ + tid * 4) = o4;
}

// ---------------------------------------------------------------------------
// RoPE: read f32 Q and KV, write bf16 Qb [B,T,HQ,128] and Kb [B,T,128]
// ---------------------------------------------------------------------------
__global__ void rope_bf16_kernel(const float* __restrict__ q, const float* __restrict__ kv,
                                 u16* __restrict__ qb, u16* __restrict__ kb)
{
    const long NQ = (long)B_ * T_ * HQ_ * 64;
    const long NK = (long)B_ * T_ * 64;
    long idx = (long)blockIdx.x * blockDim.x + threadIdx.x;
    if (idx >= NQ + NK) return;
    int i; long t; const float* src; u16* dst;
    if (idx < NQ) {
        i = idx & 63;
        long bth = idx >> 6;
        t = (bth / HQ_) % T_;
        src = q + bth * HD_ + 2 * i;
        dst = qb + bth * HD_ + 2 * i;
    } else {
        long k = idx - NQ;
        i = k & 63;
        long bt = k >> 6;
        t = bt % T_;
        src = kv + bt * (2 * HD_) + 2 * i;
        dst = kb + bt * HD_ + 2 * i;
    }
    float freq = exp2f(-(float)i * 0.20762050593046014f);  // log2(1e4)/64
    float ang = (float)t * freq;
    float sn, cs;
    sincosf(ang, &sn, &cs);
    f32x2 xv = *(const f32x2*)src;
    u16x2 yv;
    yv.x = f2bf(xv.x * cs - xv.y * sn);
    yv.y = f2bf(xv.x * sn + xv.y * cs);
    *(u16x2*)dst = yv;
}

// ---------------------------------------------------------------------------
// V transpose: KV f32 [B,T,2,128] (v half) -> Vt bf16 [B,128,T]
// ---------------------------------------------------------------------------
__global__ __launch_bounds__(256)
void vtrans_kernel(const float* __restrict__ kv, u16* __restrict__ vt)
{
    __shared__ float tile[64][65];
    const int t0 = blockIdx.x * 64, d0 = blockIdx.y * 64, b = blockIdx.z;
    const int tid = threadIdx.x;
    {
        const int tl = tid & 63, dg = tid >> 6;      // dg 0..3
        const float* vp = kv + (((long)b * T_ + t0 + tl) * 2 + 1) * HD_ + d0 + dg * 16;
#pragma unroll
        for (int j = 0; j < 4; j++) {
            f32x4 v = *(const f32x4*)(vp + j * 4);
            tile[dg * 16 + j * 4 + 0][tl] = v.x;
            tile[dg * 16 + j * 4 + 1][tl] = v.y;
            tile[dg * 16 + j * 4 + 2][tl] = v.z;
            tile[dg * 16 + j * 4 + 3][tl] = v.w;
        }
    }
    __syncthreads();
    {
        const int dl = tid >> 2, tg = (tid & 3) * 16;
        u16x8 a, c;
#pragma unroll
        for (int j = 0; j < 8; j++) a[j] = f2bf(tile[dl][tg + j]);
#pragma unroll
        for (int j = 0; j < 8; j++) c[j] = f2bf(tile[dl][tg + 8 + j]);
        u16* dst = vt + ((long)b * HD_ + d0 + dl) * T_ + t0 + tg;
        *(u16x8*)dst = a;
        *(u16x8*)(dst + 8) = c;
    }
}

// ---------------------------------------------------------------------------
// MFMA sliding-window attention v2 (unchanged from round 5)
// ---------------------------------------------------------------------------
#define PLD 72

__global__ __launch_bounds__(256)
void attn_mfma2_kernel(const u16* __restrict__ qb, const u16* __restrict__ kb,
                       const u16* __restrict__ vt, u16* __restrict__ o)
{
    __shared__ u16 Ksh[64 * 128];
    __shared__ u16 Vsh[128 * 64];
    __shared__ u16 Psh[4 * 16 * PLD];

    const int qt = blockIdx.x, h = blockIdx.y, b = blockIdx.z;
    const int q0 = qt * 64;
    const int tid = threadIdx.x;
    const int w = tid >> 6, l = tid & 63;
    const int lr = l & 15, lg = l >> 4;

    bf16x8 qfr[4];
    {
        const u16* qp = qb + (((long)b * T_ + q0 + w * 16 + lr) * HQ_ + h) * HD_;
#pragma unroll
        for (int kt = 0; kt < 4; kt++)
            qfr[kt] = *(const bf16x8*)(qp + kt * 32 + lg * 8);
    }

    int oK[4], oV[4];
#pragma unroll
    for (int i = 0; i < 4; i++) {
        int krow = w * 16 + i * 4 + (l >> 4);
        int kc8 = (l & 15) ^ (krow & 7);
        oK[i] = krow * 128 + kc8 * 8;
        int vrow = w * 32 + i * 8 + (l >> 3);
        int vc8 = (l & 7) ^ (vrow & 7);
        oV[i] = vrow * T_ + vc8 * 8;
    }
    const u16* kbase = kb + (long)b * T_ * HD_;
    const u16* vbase = vt + (long)b * HD_ * T_;

    f32x4 oacc[8];
#pragma unroll
    for (int dt = 0; dt < 8; dt++) oacc[dt] = {0.f, 0.f, 0.f, 0.f};
    float mrun[4], srun[4];
#pragma unroll
    for (int r = 0; r < 4; r++) { mrun[r] = -1e30f; srun[r] = 0.f; }

    const int kt_lo = (q0 >= W_) ? (q0 - W_) : 0;
    const int sw = lr & 7;

    for (int kt0 = kt_lo; kt0 <= q0; kt0 += 64) {
        __syncthreads();
#pragma unroll
        for (int i = 0; i < 4; i++) {
            GLOAD16(kbase + (long)kt0 * HD_ + oK[i], &Ksh[w * 2048 + i * 512]);
            GLOAD16(vbase + kt0 + oV[i], &Vsh[w * 2048 + i * 512]);
        }
        __syncthreads();

        f32x4 s[4];
#pragma unroll
        for (int ct = 0; ct < 4; ct++) {
            s[ct] = {0.f, 0.f, 0.f, 0.f};
#pragma unroll
            for (int kt = 0; kt < 4; kt++) {
                bf16x8 kf = *(const bf16x8*)&Ksh[(ct * 16 + lr) * 128 + (((kt * 4 + lg) ^ sw) * 8)];
                s[ct] = __builtin_amdgcn_mfma_f32_16x16x32_bf16(qfr[kt], kf, s[ct], 0, 0, 0);
            }
        }

        float tmax[4] = {-3e38f, -3e38f, -3e38f, -3e38f};
#pragma unroll
        for (int ct = 0; ct < 4; ct++) {
            const int kpos = kt0 + ct * 16 + lr;
#pragma unroll
            for (int r = 0; r < 4; r++) {
                const int qpos = q0 + w * 16 + lg * 4 + r;
                float v = s[ct][r] * 0.08838834764831845f;
                bool valid = (kpos <= qpos) && (kpos + W_ >= qpos);
                v = valid ? v : -3e38f;
                s[ct][r] = v;
                tmax[r] = fmaxf(tmax[r], v);
            }
        }
#pragma unroll
        for (int r = 0; r < 4; r++)
#pragma unroll
            for (int msk = 1; msk < 16; msk <<= 1)
                tmax[r] = fmaxf(tmax[r], __shfl_xor(tmax[r], msk));

        float fr[4], psum[4];
#pragma unroll
        for (int r = 0; r < 4; r++) {
            float mnew = fmaxf(mrun[r], tmax[r]);
            fr[r] = __expf(mrun[r] - mnew);
            mrun[r] = mnew;
            srun[r] *= fr[r];
            psum[r] = 0.f;
        }
#pragma unroll
        for (int dt = 0; dt < 8; dt++) {
            oacc[dt][0] *= fr[0]; oacc[dt][1] *= fr[1];
            oacc[dt][2] *= fr[2]; oacc[dt][3] *= fr[3];
        }

        u16* pw = &Psh[w * 16 * PLD];
#pragma unroll
        for (int ct = 0; ct < 4; ct++)
#pragma unroll
            for (int r = 0; r < 4; r++) {
                float p = __expf(s[ct][r] - mrun[r]);
                psum[r] += p;
                pw[(lg * 4 + r) * PLD + ct * 16 + lr] = f2bf(p);
            }
#pragma unroll
        for (int r = 0; r < 4; r++) {
#pragma unroll
            for (int msk = 1; msk < 16; msk <<= 1)
                psum[r] += __shfl_xor(psum[r], msk);
            srun[r] += psum[r];
        }

        asm volatile("s_waitcnt lgkmcnt(0)" ::: "memory");
        bf16x8 pa0 = *(const bf16x8*)&pw[lr * PLD + lg * 8];
        bf16x8 pa1 = *(const bf16x8*)&pw[lr * PLD + 32 + lg * 8];
#pragma unroll
        for (int dt = 0; dt < 8; dt++) {
            bf16x8 vf0 = *(const bf16x8*)&Vsh[(dt * 16 + lr) * 64 + ((lg ^ sw) * 8)];
            bf16x8 vf1 = *(const bf16x8*)&Vsh[(dt * 16 + lr) * 64 + (((4 + lg) ^ sw) * 8)];
            oacc[dt] = __builtin_amdgcn_mfma_f32_16x16x32_bf16(pa0, vf0, oacc[dt], 0, 0, 0);
            oacc[dt] = __builtin_amdgcn_mfma_f32_16x16x32_bf16(pa1, vf1, oacc[dt], 0, 0, 0);
        }
    }

#pragma unroll
    for (int r = 0; r < 4; r++) {
        const int qpos = q0 + w * 16 + lg * 4 + r;
        float inv = 1.f / srun[r];
        u16* op = o + ((long)b * T_ + qpos) * (HQ_ * HD_) + h * HD_;
#pragma unroll
        for (int dt = 0; dt < 8; dt++)
            op[dt * 16 + lr] = f2bf(oacc[dt][r] * inv);
    }
}

// ---------------------------------------------------------------------------
// Depthwise causal conv K=4 over bf16 u [8192,1536] -> bf16 xc
// ---------------------------------------------------------------------------
__global__ void conv_kernel(const u16* __restrict__ u, const float* __restrict__ w,
                            const float* __restrict__ bias, u16* __restrict__ xc)
{
    long idx = (long)blockIdx.x * blockDim.x + threadIdx.x;
    if (idx >= (long)B_ * T_ * HH_) return;
    int ch = (int)(idx % HH_);
    long row = idx / HH_;
    int t = (int)(row % T_);
    float acc = bias[ch];
#pragma unroll
    for (int k = 0; k < KC_; k++) {
        int ts = t - 3 + k;
        if (ts >= 0) acc += bf2f(u[(row - t + ts) * HH_ + ch]) * w[ch * KC_ + k];
    }
    xc[idx] = f2bf(acc);
}

// ---------------------------------------------------------------------------
// Chunked scan over recomputed (alpha, xin) from bf16 fg/ig/xc.
// ---------------------------------------------------------------------------
#define CS_ 64
#define NC_ (T_ / CS_)

__device__ __forceinline__ void alpha_xin(const u16 fg, const u16 ig, const u16 xc,
                                          float sp, float& a, float& xin)
{
    a = expf(-8.0f * sp * sigmoidf_(bf2f(fg)));
    xin = sqrtf(1.f - a * a + 1e-6f) * sigmoidf_(bf2f(ig)) * bf2f(xc);
}

__global__ void scan1_kernel(const u16* __restrict__ fg, const u16* __restrict__ ig,
                             const u16* __restrict__ xc, const float* __restrict__ fb,
                             float* __restrict__ P, float* __restrict__ L)
{
    long idx = (long)blockIdx.x * blockDim.x + threadIdx.x;
    if (idx >= (long)B_ * NC_ * HH_) return;
    int ch = (int)(idx % HH_);
    int chunk = (int)((idx / HH_) % NC_);
    int b = (int)(idx / ((long)HH_ * NC_));
    long base = ((long)b * T_ + chunk * CS_) * HH_ + ch;
    float f = fb[ch];
    float sp = (f > 20.f) ? f : log1pf(expf(f));
    float p = 1.f, lacc = 0.f;
    for (int i = 0; i < CS_; i++) {
        long o = base + (long)i * HH_;
        float a, xin;
        alpha_xin(fg[o], ig[o], xc[o], sp, a, xin);
        lacc = a * lacc + xin;
        p *= a;
    }
    P[idx] = p; L[idx] = lacc;
}
__global__ void scan2_kernel(const float* __restrict__ P, const float* __restrict__ L,
                             float* __restrict__ I)
{
    long idx = (long)blockIdx.x * blockDim.x + threadIdx.x;
    if (idx >= (long)B_ * HH_) return;
    int ch = (int)(idx % HH_);
    int b = (int)(idx / HH_);
    float init = 0.f;
    for (int c = 0; c < NC_; c++) {
        long o = ((long)b * NC_ + c) * HH_ + ch;
        I[o] = init;
        init = P[o] * init + L[o];
    }
}
__global__ void scan3_kernel(const u16* __restrict__ fg, const u16* __restrict__ ig,
                             const u16* __restrict__ xc, const float* __restrict__ fb,
                             const float* __restrict__ I, const u16* __restrict__ gate,
                             u16* __restrict__ glu)
{
    long idx = (long)blockIdx.x * blockDim.x + threadIdx.x;
    if (idx >= (long)B_ * NC_ * HH_) return;
    int ch = (int)(idx % HH_);
    int chunk = (int)((idx / HH_) % NC_);
    int b = (int)(idx / ((long)HH_ * NC_));
    long base = ((long)b * T_ + chunk * CS_) * HH_ + ch;
    float f = fb[ch];
    float sp = (f > 20.f) ? f : log1pf(expf(f));
    float h = I[idx];
    for (int i = 0; i < CS_; i++) {
        long o = base + (long)i * HH_;
        float a, xin;
        alpha_xin(fg[o], ig[o], xc[o], sp, a, xin);
        h = a * h + xin;
        glu[o] = f2bf(gelu_exact(bf2f(gate[o])) * h);
    }
}

// ---------------------------------------------------------------------------
// launch
// ---------------------------------------------------------------------------
static inline long cdivl(long a, long b) { return (a + b - 1) / b; }

extern "C" void kernel_launch(void* const* d_in, const int* in_sizes, int n_in,
                              void* d_out, int out_size, void* d_ws, size_t ws_size,
                              hipStream_t stream)
{
    const float* x_in   = (const float*)d_in[0];
    const float* sn_g   = (const float*)d_in[1];
    const float* q_w    = (const float*)d_in[2];
    const float* kv_w   = (const float*)d_in[3];
    const float* ao_w   = (const float*)d_in[4];
    const float* sgn_g  = (const float*)d_in[5];
    const float* sg_grow   = (const float*)d_in[6];
    const float* sg_shrink = (const float*)d_in[7];
    const float* hn_g   = (const float*)d_in[8];
    const float* h_in_w = (const float*)d_in[9];
    const float* h_conv_w = (const float*)d_in[10];
    const float* h_conv_b = (const float*)d_in[11];
    const float* h_gates_w = (const float*)d_in[12];
    const float* h_gates_b = (const float*)d_in[13];
    const float* h_forget  = (const float*)d_in[14];
    const float* h_out_w   = (const float*)d_in[15];
    const float* hgn_g  = (const float*)d_in[16];
    const float* hg_grow   = (const float*)d_in[17];
    const float* hg_shrink = (const float*)d_in[18];
    float* out = (float*)d_out;

    // ---- workspace layout ----
    char* wsb = (char*)d_ws;
    u16* Wq  = (u16*)wsb;                 // 1,048,576
    u16* Wkv = Wq  + 1048576;             // 262,144
    u16* Wao = Wkv + 262144;              // 1,048,576
    u16* Wsg = Wao + 1048576;             // 4,194,304
    u16* Wss = Wsg + 4194304;             // 2,097,152
    u16* Whi = Wss + 2097152;             // 3,145,728
    u16* Whg = Whi + 3145728;             // 4,718,592
    u16* Who = Whg + 4718592;             // 1,572,864
    u16* Wgg = Who + 1572864;             // 4,194,304
    u16* Wgs = Wgg + 4194304;             // 2,097,152
    char* ab = wsb + 48758784;            // activation arena
    u16*   XN   = (u16*)(ab + 0);                    // [8192,1024] bf16
    char*  S2   = ab + 16777216;                     // 33.5 MB slot
    char*  S3   = ab + 50331648;                     // 25.2 MB slot
    char*  S4   = ab + 75497472;                     // 25.2 MB slot
    char*  S5   = ab + 100663296;                    // 25.2 MB slot
    char*  S6   = ab + 125829120;                    // 25.2 MB slot
    float* PB   = (float*)(ab + 150994944);
    float* LB   = (float*)(ab + 151781376);
    float* IB   = (float*)(ab + 152567808);

    const long M = (long)B_ * T_;   // 8192
    dim3 blk(256);
    const float* NULF = nullptr;
    const u16*   NULB = nullptr;

    // ---- weight conversion ----
    {
        const float* srcs[10] = {q_w, kv_w, ao_w, sg_grow, sg_shrink,
                                 h_in_w, h_gates_w, h_out_w, hg_grow, hg_shrink};
        u16* dsts[10] = {Wq, Wkv, Wao, Wsg, Wss, Whi, Whg, Who, Wgg, Wgs};
        long ns[10] = {1048576, 262144, 1048576, 4194304, 2097152,
                       3145728, 4718592, 1572864, 4194304, 2097152};
        for (int i = 0; i < 10; i++)
            cvt_kernel<<<dim3(cdivl(ns[i] / 8, 256)), blk, 0, stream>>>(srcs[i], dsts[i], ns[i]);
    }

    // ---- attention sublayer ----
    {
        float* Q  = (float*)S2;                      // [8192,1024] f32
        float* KV = (float*)S3;                      // [8192,256]  f32
        u16*   Kb = (u16*)(S3 + 8388608);            // [B,T,128] bf16
        u16*   Vt = (u16*)(S3 + 10485760);           // [B,128,T] bf16
        u16*   Qb = (u16*)S4;                        // [B,T,HQ,128] bf16
        u16*   AT = (u16*)S5;                        // [8192,1024] bf16
        rmsnorm_kernel<<<dim3(M), blk, 0, stream>>>(x_in, sn_g, XN);
        gemm_bf16_kernel<0,false><<<dim3(8, 64), blk, 0, stream>>>(XN, Wq, NULF, NULF, NULB, Q, M, 1024, 1024);
        gemm_bf16_kernel<0,false><<<dim3(2, 64), blk, 0, stream>>>(XN, Wkv, NULF, NULF, NULB, KV, M, 256, 1024);
        rope_bf16_kernel<<<dim3(cdivl((long)B_ * T_ * (HQ_ + 1) * 64, 256)), blk, 0, stream>>>(Q, KV, Qb, Kb);
        vtrans_kernel<<<dim3(T_ / 64, 2, B_), blk, 0, stream>>>(KV, Vt);
        attn_mfma2_kernel<<<dim3(T_ / 64, HQ_, B_), blk, 0, stream>>>(Qb, Kb, Vt, AT);
        gemm_bf16_kernel<2,false><<<dim3(8, 64), blk, 0, stream>>>(AT, Wao, NULF, x_in, NULB, out, M, 1024, 1024);
    }

    // ---- MLP 1 ----
    {
        u16* GATE = (u16*)S2;             // [8192,2048] bf16
        rmsnorm_kernel<<<dim3(M), blk, 0, stream>>>(out, sgn_g, XN);
        gemm_bf16_kernel<0,true><<<dim3(16, 64), blk, 0, stream>>>(XN, Wsg, NULF, NULF, NULB, GATE, M, 2048, 1024);
        gemm_bf16_kernel<3,true><<<dim3(16, 64), blk, 0, stream>>>(XN, Wsg + (size_t)2048 * 1024, NULF, NULF, GATE, GATE, M, 2048, 1024);
        gemm_bf16_kernel<2,false><<<dim3(8, 64), blk, 0, stream>>>(GATE, Wss, NULF, out, NULB, out, M, 1024, 2048);
    }

    // ---- hawk ----
    {
        u16* GATEH = (u16*)S2;            // [8192,1536] bf16
        u16* U     = (u16*)S3;            // [8192,1536] bf16 (reused as GLUH)
        u16* XC    = (u16*)S4;            // [8192,1536] bf16
        u16* FG    = (u16*)S5;            // [8192,1536] bf16
        u16* IG    = (u16*)S6;            // [8192,1536] bf16
        rmsnorm_kernel<<<dim3(M), blk, 0, stream>>>(out, hn_g, XN);
        gemm_bf16_kernel<0,true><<<dim3(12, 64), blk, 0, stream>>>(XN, Whi, NULF, NULF, NULB, GATEH, M, 1536, 1024);
        gemm_bf16_kernel<0,true><<<dim3(12, 64), blk, 0, stream>>>(XN, Whi + (size_t)1536 * 1024, NULF, NULF, NULB, U, M, 1536, 1024);
        conv_kernel<<<dim3(cdivl(M * HH_, 256)), blk, 0, stream>>>(U, h_conv_w, h_conv_b, XC);
        gemm_bf16_kernel<1,true><<<dim3(12, 64), blk, 0, stream>>>(XC, Whg, h_gates_b, NULF, NULB, FG, M, 1536, 1536);
        gemm_bf16_kernel<1,true><<<dim3(12, 64), blk, 0, stream>>>(XC, Whg + (size_t)1536 * 1536, h_gates_b + 1536, NULF, NULB, IG, M, 1536, 1536);
        scan1_kernel<<<dim3(cdivl((long)B_ * NC_ * HH_, 256)), blk, 0, stream>>>(FG, IG, XC, h_forget, PB, LB);
        scan2_kernel<<<dim3(cdivl((long)B_ * HH_, 256)), blk, 0, stream>>>(PB, LB, IB);
        scan3_kernel<<<dim3(cdivl((long)B_ * NC_ * HH_, 256)), blk, 0, stream>>>(FG, IG, XC, h_forget, IB, GATEH, U);
        gemm_bf16_kernel<2,false><<<dim3(8, 64), blk, 0, stream>>>(U, Who, NULF, out, NULB, out, M, 1024, 1536);
    }

    // ---- MLP 2 ----
    {
        u16* GATE = (u16*)S2;             // [8192,2048] bf16
        rmsnorm_kernel<<<dim3(M), blk, 0, stream>>>(out, hgn_g, XN);
        gemm_bf16_kernel<0,true><<<dim3(16, 64), blk, 0, stream>>>(XN, Wgg, NULF, NULF, NULB, GATE, M, 2048, 1024);
        gemm_bf16_kernel<3,true><<<dim3(16, 64), blk, 0, stream>>>(XN, Wgg + (size_t)2048 * 1024, NULF, NULF, GATE, GATE, M, 2048, 1024);
        gemm_bf16_kernel<2,false><<<dim3(8, 64), blk, 0, stream>>>(GATE, Wgs, NULF, out, NULB, out, M, 1024, 2048);
    }
}